// Round 19
// baseline (122.715 us; speedup 1.0000x reference)
//
#include <hip/hip_runtime.h>
#include <cstdint>
#include <cstddef>

typedef unsigned short u16;
typedef __bf16 bf16x8 __attribute__((ext_vector_type(8)));
typedef float  f32x4  __attribute__((ext_vector_type(4)));
typedef float  f32x16 __attribute__((ext_vector_type(16)));
typedef unsigned u32x4 __attribute__((ext_vector_type(4)));

#define DEV __device__ __forceinline__

#define B_  2
#define S_  2048
#define DM  1024
#define H_  16
#define DK  64
#define M_  (B_ * S_)   // 4096

#if __has_builtin(__builtin_amdgcn_exp2f)
#define EXP2(x) __builtin_amdgcn_exp2f(x)
#else
#define EXP2(x) exp2f(x)
#endif

// ---------------- workspace layout (bytes) ----------------
constexpr size_t OFF_QBF  = 0;                                  // Q proj out bf16 [M][DM]
constexpr size_t OFF_KF   = OFF_QBF  + (size_t)M_ * DM * 2;     // K frag-linear (sigma rows)
constexpr size_t OFF_VF   = OFF_KF   + (size_t)M_ * DK * 2;     // V frag-linear
constexpr size_t OFF_AOBF = OFF_VF   + (size_t)M_ * DK * 2;     // attn out bf16 [M][DM]
constexpr size_t OFF_WQT  = OFF_AOBF + (size_t)M_ * DM * 2;     // Wq^T bf16 [DM][DM]
constexpr size_t OFF_WOT  = OFF_WQT  + (size_t)DM * DM * 2;     // Wo^T bf16 [DM][DM]
constexpr size_t OFF_WKT  = OFF_WOT  + (size_t)DM * DM * 2;     // Wk^T bf16 [DK][DM]
constexpr size_t OFF_WVT  = OFF_WKT  + (size_t)DK * DM * 2;     // Wv^T bf16 [DK][DM]

// ---------------- helpers ----------------
DEV u16 f2bf(float f) {                 // RNE f32 -> bf16
  unsigned u = __float_as_uint(f);
  u += 0x7fffu + ((u >> 16) & 1u);
  return (u16)(u >> 16);
}

DEV unsigned cvtpk(float lo, float hi) { // pack 2 f32 -> 2 bf16 (lo in low 16)
  return (unsigned)f2bf(lo) | ((unsigned)f2bf(hi) << 16);
}

DEV unsigned cvtpk_hw(float lo, float hi) { // v_cvt_pk_bf16_f32 (1 instr)
  unsigned r;
  asm("v_cvt_pk_bf16_f32 %0, %1, %2" : "=v"(r) : "v"(lo), "v"(hi));
  return r;
}

DEV u32x4 pack8(const float4& a, const float4& b) {
  u32x4 w;
  w[0] = cvtpk(a.x, a.y);
  w[1] = cvtpk(a.z, a.w);
  w[2] = cvtpk(b.x, b.y);
  w[3] = cvtpk(b.z, b.w);
  return w;
}

DEV void gload_lds16(const void* g, void* l) {
  __builtin_amdgcn_global_load_lds(
      (const __attribute__((address_space(1))) unsigned int*)g,
      (__attribute__((address_space(3))) unsigned int*)l, 16, 0, 0);
}

// ---------------- transpose + cast W[R][C] f32 -> WT[C][R] bf16 ----------------
__global__ void transpose_cast_kernel(const float* __restrict__ W,
                                      u16* __restrict__ WT, int R, int C) {
  __shared__ u16 tile[32][33];
  const int c0 = blockIdx.x * 32, r0 = blockIdx.y * 32;
  for (int i = threadIdx.y; i < 32; i += 8)
    tile[i][threadIdx.x] = f2bf(W[(size_t)(r0 + i) * C + c0 + threadIdx.x]);
  __syncthreads();
  for (int i = threadIdx.y; i < 32; i += 8)
    WT[(size_t)(c0 + i) * R + r0 + threadIdx.x] = tile[threadIdx.x][i];
}

// ---------------- K/V projection via MFMA, f32 input, fused fragment-linear emit ----------------
__global__ __launch_bounds__(256) void kvproj_kernel(
    const float* __restrict__ Xk, const float* __restrict__ Xv,
    const u16* __restrict__ WkT, const u16* __restrict__ WvT,
    const float* __restrict__ bk, const float* __restrict__ bv,
    u16* __restrict__ KF, u16* __restrict__ VF) {
  __shared__ __align__(16) u16 At[64 * 32];
  __shared__ __align__(16) u16 Bt[64 * 32];
  __shared__ u16 stage[64][72];
  const int sel = blockIdx.y;
  const float* X = sel ? Xv : Xk;
  const u16* WT = sel ? WvT : WkT;
  const float* bias = sel ? bv : bk;

  const int tid = threadIdx.x, wave = tid >> 6, lane = tid & 63;
  const int g = lane >> 4, c = lane & 15;
  const int wm = wave >> 1, wn = wave & 1;
  const int bm = blockIdx.x;
  f32x4 acc[2][2] = {};

  const int row = tid >> 2, sd = tid & 3;
  const float* Asrc = X + (size_t)(bm * 64 + row) * DM + sd * 8;
  const u16* Bsrc = WT + (size_t)row * DM + ((sd ^ (row & 3)) * 8);
  u16* Adst = At + row * 32 + ((sd ^ (row & 3)) * 8);   // write-side swizzle

  for (int k0 = 0; k0 < DM; k0 += 32) {
    __syncthreads();
    const float4 x0 = *(const float4*)(Asrc + k0);
    const float4 x1 = *(const float4*)(Asrc + k0 + 4);
    gload_lds16(Bsrc + k0, Bt + wave * 512);
    *(u32x4*)Adst = pack8(x0, x1);
    asm volatile("s_waitcnt vmcnt(0)" ::: "memory");
    __syncthreads();

    bf16x8 af[2], bfr[2];
#pragma unroll
    for (int mf = 0; mf < 2; ++mf) {
      const int ra = wm * 32 + mf * 16 + c;
      af[mf] = *(const bf16x8*)(At + ra * 32 + ((g ^ (ra & 3)) * 8));
    }
#pragma unroll
    for (int nf = 0; nf < 2; ++nf) {
      const int rb = wn * 32 + nf * 16 + c;
      bfr[nf] = *(const bf16x8*)(Bt + rb * 32 + ((g ^ (rb & 3)) * 8));
    }
#pragma unroll
    for (int mf = 0; mf < 2; ++mf)
#pragma unroll
      for (int nf = 0; nf < 2; ++nf)
        acc[mf][nf] = __builtin_amdgcn_mfma_f32_16x16x32_bf16(
            af[mf], bfr[nf], acc[mf][nf], 0, 0, 0);
  }

  // stage D-layout output (bias added) into LDS
  __syncthreads();
#pragma unroll
  for (int nf = 0; nf < 2; ++nf) {
    const int col = wn * 32 + nf * 16 + c;
    const float bs = bias[col];
#pragma unroll
    for (int mf = 0; mf < 2; ++mf)
#pragma unroll
      for (int r = 0; r < 4; ++r)
        stage[wm * 32 + mf * 16 + g * 4 + r][col] = f2bf(acc[mf][nf][r] + bs);
  }
  __syncthreads();

  // fragment-linear emit (same mapping as the proven repack kernel)
  u16* outF = (sel ? VF : KF) + (size_t)bm * 4096;
#pragma unroll
  for (int p = 0; p < 2; ++p) {
    const int id = tid + p * 256;          // (sub,ks,lane)
    const int sub = id >> 8, ks = (id >> 6) & 3, ln = id & 63;
    const int hi2 = ln >> 5, q = ln & 31;
    if (!sel) {   // K: sigma = swap bits 2<->3 of q
      const int sq = (q & ~12) | ((q & 4) << 1) | ((q & 8) >> 1);
      *(bf16x8*)&outF[id * 8] = *(const bf16x8*)&stage[sub * 32 + sq][ks * 16 + hi2 * 8];
    } else {      // V: transposed
      u16 tmp[8];
#pragma unroll
      for (int i = 0; i < 8; ++i)
        tmp[i] = stage[ks * 16 + hi2 * 8 + i][sub * 32 + q];
      *(bf16x8*)&outF[id * 8] = *(const bf16x8*)tmp;
    }
  }
}

// ---------------- 2-phase double-buffered 128x64 bf16 GEMM, BK=64 ----------------
// A_F32: A operand read from f32 with cast fused into reg-staged, write-side
// swizzled ds_write (T14 split: loads for t+1 issued before compute of t).
template <int OUT_F32, int A_F32>
__global__ __launch_bounds__(256) void gemm_bf16_kernel(
    const void* __restrict__ Ap, const u16* __restrict__ BT,
    const float* __restrict__ bias, void* __restrict__ Cout,
    int M, int N, int K, float oscale) {
  __shared__ __align__(16) u16 At[2][128 * 64];   // 16 KB / buf
  __shared__ __align__(16) u16 Bt[2][64 * 64];    //  8 KB / buf
  const u16*   A16 = (const u16*)Ap;
  const float* A32 = (const float*)Ap;
  const int tid = threadIdx.x, wave = tid >> 6, lane = tid & 63;
  const int bm = blockIdx.x, bn = blockIdx.y;
  const int wm = wave >> 1, wn = wave & 1;
  const int g = lane >> 4, c = lane & 15;
  f32x4 acc[4][2] = {};

  // staging maps (16B bf16 slots)
  int arow[4], asd[4], brow[2], bcol[2];
#pragma unroll
  for (int i = 0; i < 4; ++i) {
    const int sid = (i * 4 + wave) * 64 + lane;   // 0..1023
    arow[i] = sid >> 3;
    asd[i]  = sid & 7;
  }
#pragma unroll
  for (int i = 0; i < 2; ++i) {
    const int sid = (i * 4 + wave) * 64 + lane;   // 0..511
    brow[i] = sid >> 3;
    bcol[i] = ((sid & 7) ^ ((sid >> 3) & 7)) * 8;
  }
  const int nt = K >> 6;

  float4 ar0[4], ar1[4];                           // f32 A regs (A_F32 path)

  auto stage_b = [&](int buf, int t) {
    const int k0_ = t << 6;
#pragma unroll
    for (int i = 0; i < 2; ++i)
      gload_lds16(BT + (size_t)(bn * 64 + brow[i]) * K + k0_ + bcol[i],
                  &Bt[buf][(i * 4 + wave) * 512]);
  };
  auto stage_a16 = [&](int buf, int t) {
    const int k0_ = t << 6;
#pragma unroll
    for (int i = 0; i < 4; ++i)
      gload_lds16(A16 + (size_t)(bm * 128 + arow[i]) * K + k0_ +
                      ((asd[i] ^ (arow[i] & 7)) * 8),
                  &At[buf][(i * 4 + wave) * 512]);
  };
  auto stage_a32_load = [&](int t) {
    const int k0_ = t << 6;
#pragma unroll
    for (int i = 0; i < 4; ++i) {
      const float* ap_ = A32 + (size_t)(bm * 128 + arow[i]) * K + k0_ + asd[i] * 8;
      ar0[i] = *(const float4*)ap_;
      ar1[i] = *(const float4*)(ap_ + 4);
    }
  };
  auto stage_a32_write = [&](int buf) {
#pragma unroll
    for (int i = 0; i < 4; ++i)
      *(u32x4*)&At[buf][arow[i] * 64 + ((asd[i] ^ (arow[i] & 7)) * 8)] =
          pack8(ar0[i], ar1[i]);
  };

  // prologue: stage tile 0
  if constexpr (A_F32) {
    stage_a32_load(0);
    stage_b(0, 0);
    asm volatile("s_waitcnt vmcnt(0)" ::: "memory");
    stage_a32_write(0);
  } else {
    stage_a16(0, 0);
    stage_b(0, 0);
    asm volatile("s_waitcnt vmcnt(0)" ::: "memory");
  }
  __syncthreads();

  int cur = 0;
  for (int t = 0; t < nt; ++t) {
    if (t + 1 < nt) {                      // issue next-tile loads FIRST
      stage_b(cur ^ 1, t + 1);
      if constexpr (A_F32) stage_a32_load(t + 1);
      else                 stage_a16(cur ^ 1, t + 1);
    }
#pragma unroll
    for (int kk = 0; kk < 2; ++kk) {
      bf16x8 af[4], bfr[2];
#pragma unroll
      for (int mf = 0; mf < 4; ++mf) {
        const int row = wm * 64 + mf * 16 + c;
        af[mf] = *(const bf16x8*)(&At[cur][row * 64 + ((kk * 4 + g) ^ (row & 7)) * 8]);
      }
#pragma unroll
      for (int nf = 0; nf < 2; ++nf) {
        const int row = wn * 32 + nf * 16 + c;
        bfr[nf] = *(const bf16x8*)(&Bt[cur][row * 64 + ((kk * 4 + g) ^ (row & 7)) * 8]);
      }
#pragma unroll
      for (int mf = 0; mf < 4; ++mf)
#pragma unroll
        for (int nf = 0; nf < 2; ++nf)
          acc[mf][nf] = __builtin_amdgcn_mfma_f32_16x16x32_bf16(
              af[mf], bfr[nf], acc[mf][nf], 0, 0, 0);
    }
    asm volatile("s_waitcnt vmcnt(0)" ::: "memory");  // next tile landed
    if constexpr (A_F32) {
      if (t + 1 < nt) stage_a32_write(cur ^ 1);
    }
    __syncthreads();
    cur ^= 1;
  }

  const int colb = bn * 64 + wn * 32 + c;
  const int rowb = bm * 128 + wm * 64 + g * 4;
#pragma unroll
  for (int nf = 0; nf < 2; ++nf) {
    float bs = bias[colb + nf * 16];
#pragma unroll
    for (int mf = 0; mf < 4; ++mf) {
#pragma unroll
      for (int r = 0; r < 4; ++r) {
        size_t idx = (size_t)(rowb + mf * 16 + r) * N + colb + nf * 16;
        float v = (acc[mf][nf][r] + bs) * oscale;
        if (OUT_F32) ((float*)Cout)[idx] = v;
        else         ((u16*)Cout)[idx]   = f2bf(v);
      }
    }
  }
}

// ---------------- attn: per-tile load / compute building blocks (R14 proven) ----------------
DEV void attn_load(const u16* kp, const u16* vp, bf16x8* kf, bf16x8* vf) {
#pragma unroll
  for (int i = 0; i < 4; ++i) {
    kf[i]     = *(const bf16x8*)(kp + i * 512);
    kf[4 + i] = *(const bf16x8*)(kp + 2048 + i * 512);
    vf[i]     = *(const bf16x8*)(vp + i * 512);
    vf[4 + i] = *(const bf16x8*)(vp + 2048 + i * 512);
  }
}

DEV void attn_comp(int t, int qrow, int hi, bool evenU, int nt,
                   const bf16x8* kf, const bf16x8* vf, const bf16x8* qf,
                   f32x16& acc0, f32x16& acc1, float& l_) {
  const int kv0 = t * 64;
  const bool diag = (t == nt - 1);
  const bool skipHi = diag && evenU;

  f32x16 sf0 = {}, sf1 = {};
  __builtin_amdgcn_s_setprio(1);
#pragma unroll
  for (int ks = 0; ks < 4; ++ks)
    sf0 = __builtin_amdgcn_mfma_f32_32x32x16_bf16(kf[ks], qf[ks], sf0, 0, 0, 0);
  if (!skipHi) {
#pragma unroll
    for (int ks = 0; ks < 4; ++ks)
      sf1 = __builtin_amdgcn_mfma_f32_32x32x16_bf16(kf[4 + ks], qf[ks], sf1, 0, 0, 0);
  }
  __builtin_amdgcn_s_setprio(0);

  if (diag) {   // causal mask; kv of reg r = 16*(r>>3) + 8*hi + (r&7)
#pragma unroll
    for (int r = 0; r < 16; ++r) {
      const int kvl = (r & 7) + 8 * hi + 16 * (r >> 3);
      if (kv0 + kvl > qrow)      sf0[r] = -1e30f;
      if (kv0 + 32 + kvl > qrow) sf1[r] = -1e30f;
    }
  }

  float rs0 = 0.f, rs1 = 0.f;
#pragma unroll
  for (int r = 0; r < 8; ++r)  { float e = EXP2(sf0[r]); sf0[r] = e; rs0 += e; }
#pragma unroll
  for (int r = 8; r < 16; ++r) { float e = EXP2(sf0[r]); sf0[r] = e; rs1 += e; }
  if (!skipHi) {
#pragma unroll
    for (int r = 0; r < 8; ++r)  { float e = EXP2(sf1[r]); sf1[r] = e; rs0 += e; }
#pragma unroll
    for (int r = 8; r < 16; ++r) { float e = EXP2(sf1[r]); sf1[r] = e; rs1 += e; }
  }
  l_ += rs0 + rs1;

  __builtin_amdgcn_s_setprio(1);
#pragma unroll
  for (int at = 0; at < 2; ++at) {
    if (at == 1 && skipHi) break;
    const f32x16& sfv = at ? sf1 : sf0;
#pragma unroll
    for (int half = 0; half < 2; ++half) {
      const int rb = half * 8;
      u32x4 pw;
      pw[0] = cvtpk_hw(sfv[rb + 0], sfv[rb + 1]);
      pw[1] = cvtpk_hw(sfv[rb + 2], sfv[rb + 3]);
      pw[2] = cvtpk_hw(sfv[rb + 4], sfv[rb + 5]);
      pw[3] = cvtpk_hw(sfv[rb + 6], sfv[rb + 7]);
      const bf16x8 pa = __builtin_bit_cast(bf16x8, pw);
      const int ksg = at * 2 + half;
      acc0 = __builtin_amdgcn_mfma_f32_32x32x16_bf16(pa, vf[ksg], acc0, 0, 0, 0);
      acc1 = __builtin_amdgcn_mfma_f32_32x32x16_bf16(pa, vf[4 + ksg], acc1, 0, 0, 0);
    }
  }
  __builtin_amdgcn_s_setprio(0);
}

// ---------------- causal MQA flash attention: split-KV, 2-stage pipeline ----------------
// LPT: u = 63 - j (longest blocks dispatched first -> better tail packing).
__global__ __launch_bounds__(256, 2) void attn_kernel(
    const u16* __restrict__ Q,   // [B*S][DM] bf16 (head h at col h*64), pre-scaled
    const u16* __restrict__ KF,  // fragment-linear K (sigma-permuted rows)
    const u16* __restrict__ VF,  // fragment-linear V
    u16* __restrict__ O) {       // [B*S][DM] bf16
  __shared__ float Ll[4][32];
  __shared__ float Lacc[4][32][64];   // 32 KB

  const int j = blockIdx.x, h = blockIdx.y, b = blockIdx.z;
  const int wave = threadIdx.x >> 6, lane = threadIdx.x & 63;
  const int q31 = lane & 31, hi = lane >> 5;

  const int u = 63 - j;                  // LPT order
  const int qrow = u * 32 + q31;
  const int nt = (u + 2) >> 1;           // kv tiles for this q-unit
  const bool evenU = !(u & 1);

  const u16* Qp = Q + (size_t)(b * S_ + qrow) * DM + h * DK;
  bf16x8 qf[4];
#pragma unroll
  for (int ks = 0; ks < 4; ++ks)
    qf[ks] = *(const bf16x8*)(Qp + ks * 16 + hi * 8);

  f32x16 acc0 = {}, acc1 = {};
  float l_ = 0.f;

  const u16* kfb = KF + (size_t)(b * 32) * 4096 + lane * 8;
  const u16* vfb = VF + (size_t)(b * 32) * 4096 + lane * 8;

  bf16x8 kA[8], vA[8], kB[8], vB[8];
  int t = wave;
  if (t < nt)
    attn_load(kfb + (size_t)t * 4096, vfb + (size_t)t * 4096, kA, vA);
  for (; t < nt; t += 8) {
    const int t1 = t + 4;
    if (t1 < nt)
      attn_load(kfb + (size_t)t1 * 4096, vfb + (size_t)t1 * 4096, kB, vB);
    attn_comp(t, qrow, hi, evenU, nt, kA, vA, qf, acc0, acc1, l_);
    if (t1 < nt) {
      const int t2 = t1 + 4;
      if (t2 < nt)
        attn_load(kfb + (size_t)t2 * 4096, vfb + (size_t)t2 * 4096, kA, vA);
      attn_comp(t1, qrow, hi, evenU, nt, kB, vB, qf, acc0, acc1, l_);
    }
  }

  // one lane^32 combine of the per-lane l partials
  l_ += __shfl_xor(l_, 32);

  // ---- block-level combine of the 4 partials (plain sums) ----
  if (hi == 0) Ll[wave][q31] = l_;
  __syncthreads();

#pragma unroll
  for (int r = 0; r < 16; ++r) {
    const int rr = (r & 3) + 8 * (r >> 2) + 4 * hi;   // acc row (PV D layout)
    Lacc[wave][rr][q31]      = acc0[r];
    Lacc[wave][rr][32 + q31] = acc1[r];
  }
  __syncthreads();

  const int row = wave * 8 + (lane >> 3);
  const int dv0 = (lane & 7) * 8;
  const float Lr = Ll[0][row] + Ll[1][row] + Ll[2][row] + Ll[3][row];
  const float linv = 1.f / Lr;
  u16 ov[8];
#pragma unroll
  for (int i = 0; i < 8; ++i) {
    const float v = (Lacc[0][row][dv0 + i] + Lacc[1][row][dv0 + i] +
                     Lacc[2][row][dv0 + i] + Lacc[3][row][dv0 + i]) * linv;
    ov[i] = f2bf(v);
  }
  u16* Op = O + (size_t)(b * S_ + u * 32 + row) * DM + h * DK + dv0;
  *(bf16x8*)Op = *(const bf16x8*)ov;
}

// ---------------- launch ----------------
extern "C" void kernel_launch(void* const* d_in, const int* in_sizes, int n_in,
                              void* d_out, int out_size, void* d_ws, size_t ws_size,
                              hipStream_t stream) {
  const float* in_q = (const float*)d_in[0];
  const float* in_k = (const float*)d_in[1];
  const float* in_v = (const float*)d_in[2];
  const float* Wq   = (const float*)d_in[3];
  const float* bq   = (const float*)d_in[4];
  const float* Wk   = (const float*)d_in[5];
  const float* bk   = (const float*)d_in[6];
  const float* Wv   = (const float*)d_in[7];
  const float* bv   = (const float*)d_in[8];
  const float* Wo   = (const float*)d_in[9];
  const float* bo   = (const float*)d_in[10];

  char* ws  = (char*)d_ws;
  u16* Qbf  = (u16*)(ws + OFF_QBF);
  u16* KFp  = (u16*)(ws + OFF_KF);
  u16* VFp  = (u16*)(ws + OFF_VF);
  u16* AObf = (u16*)(ws + OFF_AOBF);
  u16* WqT  = (u16*)(ws + OFF_WQT);
  u16* WoT  = (u16*)(ws + OFF_WOT);
  u16* WkT  = (u16*)(ws + OFF_WKT);
  u16* WvT  = (u16*)(ws + OFF_WVT);

  transpose_cast_kernel<<<dim3(32, 32), dim3(32, 8), 0, stream>>>(Wq, WqT, DM, DM);
  transpose_cast_kernel<<<dim3(32, 32), dim3(32, 8), 0, stream>>>(Wo, WoT, DM, DM);
  transpose_cast_kernel<<<dim3(2, 32),  dim3(32, 8), 0, stream>>>(Wk, WkT, DM, DK);
  transpose_cast_kernel<<<dim3(2, 32),  dim3(32, 8), 0, stream>>>(Wv, WvT, DM, DK);

  // K/V projection reading f32 inputs directly (cast fused into staging)
  kvproj_kernel<<<dim3(M_ / 64, 2), 256, 0, stream>>>(
      in_k, in_v, WkT, WvT, bk, bv, KFp, VFp);

  // Q projection from f32 input, pre-scaled by 1/sqrt(dk)*log2(e)
  gemm_bf16_kernel<0, 1><<<dim3(M_ / 128, DM / 64), 256, 0, stream>>>(
      in_q, WqT, bq, Qbf, M_, DM, DM, 0.125f * 1.44269504088896f);

  attn_kernel<<<dim3(64, H_, B_), 256, 0, stream>>>(Qbf, KFp, VFp, AObf);

  gemm_bf16_kernel<1, 0><<<dim3(M_ / 128, DM / 64), 256, 0, stream>>>(
      AObf, WoT, bo, d_out, M_, DM, DM, 1.0f);
}

// Round 20
// 117.034 us; speedup vs baseline: 1.0485x; 1.0485x over previous
//
#include <hip/hip_runtime.h>
#include <cstdint>
#include <cstddef>

typedef unsigned short u16;
typedef __bf16 bf16x8 __attribute__((ext_vector_type(8)));
typedef float  f32x4  __attribute__((ext_vector_type(4)));
typedef float  f32x16 __attribute__((ext_vector_type(16)));
typedef unsigned u32x4 __attribute__((ext_vector_type(4)));

#define DEV __device__ __forceinline__

#define B_  2
#define S_  2048
#define DM  1024
#define H_  16
#define DK  64
#define M_  (B_ * S_)   // 4096

#if __has_builtin(__builtin_amdgcn_exp2f)
#define EXP2(x) __builtin_amdgcn_exp2f(x)
#else
#define EXP2(x) exp2f(x)
#endif

// ---------------- workspace layout (bytes) ----------------
constexpr size_t OFF_QBF  = 0;                                  // Q proj out bf16 [M][DM]
constexpr size_t OFF_KF   = OFF_QBF  + (size_t)M_ * DM * 2;     // K frag-linear (sigma rows)
constexpr size_t OFF_VF   = OFF_KF   + (size_t)M_ * DK * 2;     // V frag-linear
constexpr size_t OFF_AOBF = OFF_VF   + (size_t)M_ * DK * 2;     // attn out bf16 [M][DM]
constexpr size_t OFF_WQT  = OFF_AOBF + (size_t)M_ * DM * 2;     // Wq^T bf16 [DM][DM]
constexpr size_t OFF_WOT  = OFF_WQT  + (size_t)DM * DM * 2;     // Wo^T bf16 [DM][DM]
constexpr size_t OFF_WKT  = OFF_WOT  + (size_t)DM * DM * 2;     // Wk^T bf16 [DK][DM]
constexpr size_t OFF_WVT  = OFF_WKT  + (size_t)DK * DM * 2;     // Wv^T bf16 [DK][DM]
constexpr size_t OFF_XQBF = OFF_WVT  + (size_t)DK * DM * 2;     // inputs_q bf16 [M][DM]

// ---------------- helpers ----------------
DEV u16 f2bf(float f) {                 // RNE f32 -> bf16
  unsigned u = __float_as_uint(f);
  u += 0x7fffu + ((u >> 16) & 1u);
  return (u16)(u >> 16);
}

DEV unsigned cvtpk(float lo, float hi) { // pack 2 f32 -> 2 bf16 (lo in low 16)
  return (unsigned)f2bf(lo) | ((unsigned)f2bf(hi) << 16);
}

DEV unsigned cvtpk_hw(float lo, float hi) { // v_cvt_pk_bf16_f32 (1 instr)
  unsigned r;
  asm("v_cvt_pk_bf16_f32 %0, %1, %2" : "=v"(r) : "v"(lo), "v"(hi));
  return r;
}

DEV u32x4 pack8(const float4& a, const float4& b) {
  u32x4 w;
  w[0] = cvtpk(a.x, a.y);
  w[1] = cvtpk(a.z, a.w);
  w[2] = cvtpk(b.x, b.y);
  w[3] = cvtpk(b.z, b.w);
  return w;
}

DEV void gload_lds16(const void* g, void* l) {
  __builtin_amdgcn_global_load_lds(
      (const __attribute__((address_space(1))) unsigned int*)g,
      (__attribute__((address_space(3))) unsigned int*)l, 16, 0, 0);
}

// ---------------- cast f32 -> bf16, 8 elems/thread ----------------
__global__ __launch_bounds__(256) void cast_bf16_kernel(
    const float* __restrict__ in, u16* __restrict__ out, int n8) {
  const int stride = gridDim.x * blockDim.x;
  for (int i = blockIdx.x * blockDim.x + threadIdx.x; i < n8; i += stride) {
    float4 a = ((const float4*)in)[2 * i];
    float4 b = ((const float4*)in)[2 * i + 1];
    ((u32x4*)out)[i] = pack8(a, b);
  }
}

// ---------------- transpose + cast W[R][C] f32 -> WT[C][R] bf16 ----------------
__global__ void transpose_cast_kernel(const float* __restrict__ W,
                                      u16* __restrict__ WT, int R, int C) {
  __shared__ u16 tile[32][33];
  const int c0 = blockIdx.x * 32, r0 = blockIdx.y * 32;
  for (int i = threadIdx.y; i < 32; i += 8)
    tile[i][threadIdx.x] = f2bf(W[(size_t)(r0 + i) * C + c0 + threadIdx.x]);
  __syncthreads();
  for (int i = threadIdx.y; i < 32; i += 8)
    WT[(size_t)(c0 + i) * R + r0 + threadIdx.x] = tile[threadIdx.x][i];
}

// ---------------- K/V projection via MFMA, f32 input, fused fragment-linear emit ----------------
__global__ __launch_bounds__(256) void kvproj_kernel(
    const float* __restrict__ Xk, const float* __restrict__ Xv,
    const u16* __restrict__ WkT, const u16* __restrict__ WvT,
    const float* __restrict__ bk, const float* __restrict__ bv,
    u16* __restrict__ KF, u16* __restrict__ VF) {
  __shared__ __align__(16) u16 At[64 * 32];
  __shared__ __align__(16) u16 Bt[64 * 32];
  __shared__ u16 stage[64][72];
  const int sel = blockIdx.y;
  const float* X = sel ? Xv : Xk;
  const u16* WT = sel ? WvT : WkT;
  const float* bias = sel ? bv : bk;

  const int tid = threadIdx.x, wave = tid >> 6, lane = tid & 63;
  const int g = lane >> 4, c = lane & 15;
  const int wm = wave >> 1, wn = wave & 1;
  const int bm = blockIdx.x;
  f32x4 acc[2][2] = {};

  const int row = tid >> 2, sd = tid & 3;
  const float* Asrc = X + (size_t)(bm * 64 + row) * DM + sd * 8;
  const u16* Bsrc = WT + (size_t)row * DM + ((sd ^ (row & 3)) * 8);
  u16* Adst = At + row * 32 + ((sd ^ (row & 3)) * 8);   // write-side swizzle

  for (int k0 = 0; k0 < DM; k0 += 32) {
    __syncthreads();
    const float4 x0 = *(const float4*)(Asrc + k0);
    const float4 x1 = *(const float4*)(Asrc + k0 + 4);
    gload_lds16(Bsrc + k0, Bt + wave * 512);
    *(u32x4*)Adst = pack8(x0, x1);
    asm volatile("s_waitcnt vmcnt(0)" ::: "memory");
    __syncthreads();

    bf16x8 af[2], bfr[2];
#pragma unroll
    for (int mf = 0; mf < 2; ++mf) {
      const int ra = wm * 32 + mf * 16 + c;
      af[mf] = *(const bf16x8*)(At + ra * 32 + ((g ^ (ra & 3)) * 8));
    }
#pragma unroll
    for (int nf = 0; nf < 2; ++nf) {
      const int rb = wn * 32 + nf * 16 + c;
      bfr[nf] = *(const bf16x8*)(Bt + rb * 32 + ((g ^ (rb & 3)) * 8));
    }
#pragma unroll
    for (int mf = 0; mf < 2; ++mf)
#pragma unroll
      for (int nf = 0; nf < 2; ++nf)
        acc[mf][nf] = __builtin_amdgcn_mfma_f32_16x16x32_bf16(
            af[mf], bfr[nf], acc[mf][nf], 0, 0, 0);
  }

  // stage D-layout output (bias added) into LDS
  __syncthreads();
#pragma unroll
  for (int nf = 0; nf < 2; ++nf) {
    const int col = wn * 32 + nf * 16 + c;
    const float bs = bias[col];
#pragma unroll
    for (int mf = 0; mf < 2; ++mf)
#pragma unroll
      for (int r = 0; r < 4; ++r)
        stage[wm * 32 + mf * 16 + g * 4 + r][col] = f2bf(acc[mf][nf][r] + bs);
  }
  __syncthreads();

  // fragment-linear emit (same mapping as the proven repack kernel)
  u16* outF = (sel ? VF : KF) + (size_t)bm * 4096;
#pragma unroll
  for (int p = 0; p < 2; ++p) {
    const int id = tid + p * 256;          // (sub,ks,lane)
    const int sub = id >> 8, ks = (id >> 6) & 3, ln = id & 63;
    const int hi2 = ln >> 5, q = ln & 31;
    if (!sel) {   // K: sigma = swap bits 2<->3 of q
      const int sq = (q & ~12) | ((q & 4) << 1) | ((q & 8) >> 1);
      *(bf16x8*)&outF[id * 8] = *(const bf16x8*)&stage[sub * 32 + sq][ks * 16 + hi2 * 8];
    } else {      // V: transposed
      u16 tmp[8];
#pragma unroll
      for (int i = 0; i < 8; ++i)
        tmp[i] = stage[ks * 16 + hi2 * 8 + i][sub * 32 + q];
      *(bf16x8*)&outF[id * 8] = *(const bf16x8*)tmp;
    }
  }
}

// ---------------- 2-phase double-buffered 128x64 bf16 GEMM, BK=64 ----------------
template <int OUT_F32>
__global__ __launch_bounds__(256) void gemm_bf16_kernel(
    const u16* __restrict__ A, const u16* __restrict__ BT,
    const float* __restrict__ bias, void* __restrict__ Cout,
    int M, int N, int K, float oscale) {
  __shared__ __align__(16) u16 At[2][128 * 64];   // 16 KB / buf
  __shared__ __align__(16) u16 Bt[2][64 * 64];    //  8 KB / buf
  const int tid = threadIdx.x, wave = tid >> 6, lane = tid & 63;
  const int bm = blockIdx.x, bn = blockIdx.y;
  const int wm = wave >> 1, wn = wave & 1;
  const int g = lane >> 4, c = lane & 15;
  f32x4 acc[4][2] = {};

  // staging maps (16B bf16 slots, source col pre-swizzled; linear LDS dest)
  int arow[4], acol[4], brow[2], bcol[2];
#pragma unroll
  for (int i = 0; i < 4; ++i) {
    const int sid = (i * 4 + wave) * 64 + lane;   // 0..1023
    arow[i] = sid >> 3;
    acol[i] = ((sid & 7) ^ ((sid >> 3) & 7)) * 8;
  }
#pragma unroll
  for (int i = 0; i < 2; ++i) {
    const int sid = (i * 4 + wave) * 64 + lane;   // 0..511
    brow[i] = sid >> 3;
    bcol[i] = ((sid & 7) ^ ((sid >> 3) & 7)) * 8;
  }
  const int nt = K >> 6;

  auto stage_g = [&](int buf, int t) {
    const int k0_ = t << 6;
#pragma unroll
    for (int i = 0; i < 4; ++i)
      gload_lds16(A + (size_t)(bm * 128 + arow[i]) * K + k0_ + acol[i],
                  &At[buf][(i * 4 + wave) * 512]);
#pragma unroll
    for (int i = 0; i < 2; ++i)
      gload_lds16(BT + (size_t)(bn * 64 + brow[i]) * K + k0_ + bcol[i],
                  &Bt[buf][(i * 4 + wave) * 512]);
  };

  stage_g(0, 0);
  asm volatile("s_waitcnt vmcnt(0)" ::: "memory");
  __syncthreads();

  int cur = 0;
  for (int t = 0; t < nt; ++t) {
    if (t + 1 < nt) stage_g(cur ^ 1, t + 1);   // issue next-tile loads FIRST
#pragma unroll
    for (int kk = 0; kk < 2; ++kk) {
      bf16x8 af[4], bfr[2];
#pragma unroll
      for (int mf = 0; mf < 4; ++mf) {
        const int row = wm * 64 + mf * 16 + c;
        af[mf] = *(const bf16x8*)(&At[cur][row * 64 + ((kk * 4 + g) ^ (row & 7)) * 8]);
      }
#pragma unroll
      for (int nf = 0; nf < 2; ++nf) {
        const int row = wn * 32 + nf * 16 + c;
        bfr[nf] = *(const bf16x8*)(&Bt[cur][row * 64 + ((kk * 4 + g) ^ (row & 7)) * 8]);
      }
#pragma unroll
      for (int mf = 0; mf < 4; ++mf)
#pragma unroll
        for (int nf = 0; nf < 2; ++nf)
          acc[mf][nf] = __builtin_amdgcn_mfma_f32_16x16x32_bf16(
              af[mf], bfr[nf], acc[mf][nf], 0, 0, 0);
    }
    asm volatile("s_waitcnt vmcnt(0)" ::: "memory");  // next tile landed
    __syncthreads();
    cur ^= 1;
  }

  const int colb = bn * 64 + wn * 32 + c;
  const int rowb = bm * 128 + wm * 64 + g * 4;
#pragma unroll
  for (int nf = 0; nf < 2; ++nf) {
    float bs = bias[colb + nf * 16];
#pragma unroll
    for (int mf = 0; mf < 4; ++mf) {
#pragma unroll
      for (int r = 0; r < 4; ++r) {
        size_t idx = (size_t)(rowb + mf * 16 + r) * N + colb + nf * 16;
        float v = (acc[mf][nf][r] + bs) * oscale;
        if (OUT_F32) ((float*)Cout)[idx] = v;
        else         ((u16*)Cout)[idx]   = f2bf(v);
      }
    }
  }
}

// ---------------- attn: per-tile load / compute building blocks (R14 proven) ----------------
DEV void attn_load(const u16* kp, const u16* vp, bf16x8* kf, bf16x8* vf) {
#pragma unroll
  for (int i = 0; i < 4; ++i) {
    kf[i]     = *(const bf16x8*)(kp + i * 512);
    kf[4 + i] = *(const bf16x8*)(kp + 2048 + i * 512);
    vf[i]     = *(const bf16x8*)(vp + i * 512);
    vf[4 + i] = *(const bf16x8*)(vp + 2048 + i * 512);
  }
}

DEV void attn_comp(int t, int qrow, int hi, bool evenU, int nt,
                   const bf16x8* kf, const bf16x8* vf, const bf16x8* qf,
                   f32x16& acc0, f32x16& acc1, float& l_) {
  const int kv0 = t * 64;
  const bool diag = (t == nt - 1);
  const bool skipHi = diag && evenU;

  f32x16 sf0 = {}, sf1 = {};
  __builtin_amdgcn_s_setprio(1);
#pragma unroll
  for (int ks = 0; ks < 4; ++ks)
    sf0 = __builtin_amdgcn_mfma_f32_32x32x16_bf16(kf[ks], qf[ks], sf0, 0, 0, 0);
  if (!skipHi) {
#pragma unroll
    for (int ks = 0; ks < 4; ++ks)
      sf1 = __builtin_amdgcn_mfma_f32_32x32x16_bf16(kf[4 + ks], qf[ks], sf1, 0, 0, 0);
  }
  __builtin_amdgcn_s_setprio(0);

  if (diag) {   // causal mask; kv of reg r = 16*(r>>3) + 8*hi + (r&7)
#pragma unroll
    for (int r = 0; r < 16; ++r) {
      const int kvl = (r & 7) + 8 * hi + 16 * (r >> 3);
      if (kv0 + kvl > qrow)      sf0[r] = -1e30f;
      if (kv0 + 32 + kvl > qrow) sf1[r] = -1e30f;
    }
  }

  float rs0 = 0.f, rs1 = 0.f;
#pragma unroll
  for (int r = 0; r < 8; ++r)  { float e = EXP2(sf0[r]); sf0[r] = e; rs0 += e; }
#pragma unroll
  for (int r = 8; r < 16; ++r) { float e = EXP2(sf0[r]); sf0[r] = e; rs1 += e; }
  if (!skipHi) {
#pragma unroll
    for (int r = 0; r < 8; ++r)  { float e = EXP2(sf1[r]); sf1[r] = e; rs0 += e; }
#pragma unroll
    for (int r = 8; r < 16; ++r) { float e = EXP2(sf1[r]); sf1[r] = e; rs1 += e; }
  }
  l_ += rs0 + rs1;

  __builtin_amdgcn_s_setprio(1);
#pragma unroll
  for (int at = 0; at < 2; ++at) {
    if (at == 1 && skipHi) break;
    const f32x16& sfv = at ? sf1 : sf0;
#pragma unroll
    for (int half = 0; half < 2; ++half) {
      const int rb = half * 8;
      u32x4 pw;
      pw[0] = cvtpk_hw(sfv[rb + 0], sfv[rb + 1]);
      pw[1] = cvtpk_hw(sfv[rb + 2], sfv[rb + 3]);
      pw[2] = cvtpk_hw(sfv[rb + 4], sfv[rb + 5]);
      pw[3] = cvtpk_hw(sfv[rb + 6], sfv[rb + 7]);
      const bf16x8 pa = __builtin_bit_cast(bf16x8, pw);
      const int ksg = at * 2 + half;
      acc0 = __builtin_amdgcn_mfma_f32_32x32x16_bf16(pa, vf[ksg], acc0, 0, 0, 0);
      acc1 = __builtin_amdgcn_mfma_f32_32x32x16_bf16(pa, vf[4 + ksg], acc1, 0, 0, 0);
    }
  }
  __builtin_amdgcn_s_setprio(0);
}

// ---------------- causal MQA flash attention: split-KV, 2-stage pipeline, LPT ----------------
__global__ __launch_bounds__(256, 2) void attn_kernel(
    const u16* __restrict__ Q,   // [B*S][DM] bf16 (head h at col h*64), pre-scaled
    const u16* __restrict__ KF,  // fragment-linear K (sigma-permuted rows)
    const u16* __restrict__ VF,  // fragment-linear V
    u16* __restrict__ O) {       // [B*S][DM] bf16
  __shared__ float Ll[4][32];
  __shared__ float Lacc[4][32][64];   // 32 KB

  const int j = blockIdx.x, h = blockIdx.y, b = blockIdx.z;
  const int wave = threadIdx.x >> 6, lane = threadIdx.x & 63;
  const int q31 = lane & 31, hi = lane >> 5;

  const int u = 63 - j;                  // LPT order
  const int qrow = u * 32 + q31;
  const int nt = (u + 2) >> 1;           // kv tiles for this q-unit
  const bool evenU = !(u & 1);

  const u16* Qp = Q + (size_t)(b * S_ + qrow) * DM + h * DK;
  bf16x8 qf[4];
#pragma unroll
  for (int ks = 0; ks < 4; ++ks)
    qf[ks] = *(const bf16x8*)(Qp + ks * 16 + hi * 8);

  f32x16 acc0 = {}, acc1 = {};
  float l_ = 0.f;

  const u16* kfb = KF + (size_t)(b * 32) * 4096 + lane * 8;
  const u16* vfb = VF + (size_t)(b * 32) * 4096 + lane * 8;

  bf16x8 kA[8], vA[8], kB[8], vB[8];
  int t = wave;
  if (t < nt)
    attn_load(kfb + (size_t)t * 4096, vfb + (size_t)t * 4096, kA, vA);
  for (; t < nt; t += 8) {
    const int t1 = t + 4;
    if (t1 < nt)
      attn_load(kfb + (size_t)t1 * 4096, vfb + (size_t)t1 * 4096, kB, vB);
    attn_comp(t, qrow, hi, evenU, nt, kA, vA, qf, acc0, acc1, l_);
    if (t1 < nt) {
      const int t2 = t1 + 4;
      if (t2 < nt)
        attn_load(kfb + (size_t)t2 * 4096, vfb + (size_t)t2 * 4096, kA, vA);
      attn_comp(t1, qrow, hi, evenU, nt, kB, vB, qf, acc0, acc1, l_);
    }
  }

  // one lane^32 combine of the per-lane l partials
  l_ += __shfl_xor(l_, 32);

  // ---- block-level combine of the 4 partials (plain sums) ----
  if (hi == 0) Ll[wave][q31] = l_;
  __syncthreads();

#pragma unroll
  for (int r = 0; r < 16; ++r) {
    const int rr = (r & 3) + 8 * (r >> 2) + 4 * hi;   // acc row (PV D layout)
    Lacc[wave][rr][q31]      = acc0[r];
    Lacc[wave][rr][32 + q31] = acc1[r];
  }
  __syncthreads();

  const int row = wave * 8 + (lane >> 3);
  const int dv0 = (lane & 7) * 8;
  const float Lr = Ll[0][row] + Ll[1][row] + Ll[2][row] + Ll[3][row];
  const float linv = 1.f / Lr;
  u16 ov[8];
#pragma unroll
  for (int i = 0; i < 8; ++i) {
    const float v = (Lacc[0][row][dv0 + i] + Lacc[1][row][dv0 + i] +
                     Lacc[2][row][dv0 + i] + Lacc[3][row][dv0 + i]) * linv;
    ov[i] = f2bf(v);
  }
  u16* Op = O + (size_t)(b * S_ + u * 32 + row) * DM + h * DK + dv0;
  *(bf16x8*)Op = *(const bf16x8*)ov;
}

// ---------------- launch ----------------
extern "C" void kernel_launch(void* const* d_in, const int* in_sizes, int n_in,
                              void* d_out, int out_size, void* d_ws, size_t ws_size,
                              hipStream_t stream) {
  const float* in_q = (const float*)d_in[0];
  const float* in_k = (const float*)d_in[1];
  const float* in_v = (const float*)d_in[2];
  const float* Wq   = (const float*)d_in[3];
  const float* bq   = (const float*)d_in[4];
  const float* Wk   = (const float*)d_in[5];
  const float* bk   = (const float*)d_in[6];
  const float* Wv   = (const float*)d_in[7];
  const float* bv   = (const float*)d_in[8];
  const float* Wo   = (const float*)d_in[9];
  const float* bo   = (const float*)d_in[10];

  char* ws  = (char*)d_ws;
  u16* Qbf  = (u16*)(ws + OFF_QBF);
  u16* KFp  = (u16*)(ws + OFF_KF);
  u16* VFp  = (u16*)(ws + OFF_VF);
  u16* AObf = (u16*)(ws + OFF_AOBF);
  u16* WqT  = (u16*)(ws + OFF_WQT);
  u16* WoT  = (u16*)(ws + OFF_WOT);
  u16* WkT  = (u16*)(ws + OFF_WKT);
  u16* WvT  = (u16*)(ws + OFF_WVT);
  u16* Xqbf = (u16*)(ws + OFF_XQBF);

  cast_bf16_kernel<<<2048, 256, 0, stream>>>(in_q, Xqbf, M_ * DM / 8);

  transpose_cast_kernel<<<dim3(32, 32), dim3(32, 8), 0, stream>>>(Wq, WqT, DM, DM);
  transpose_cast_kernel<<<dim3(32, 32), dim3(32, 8), 0, stream>>>(Wo, WoT, DM, DM);
  transpose_cast_kernel<<<dim3(2, 32),  dim3(32, 8), 0, stream>>>(Wk, WkT, DM, DK);
  transpose_cast_kernel<<<dim3(2, 32),  dim3(32, 8), 0, stream>>>(Wv, WvT, DM, DK);

  // K/V projection reading f32 inputs directly (cast fused into staging)
  kvproj_kernel<<<dim3(M_ / 64, 2), 256, 0, stream>>>(
      in_k, in_v, WkT, WvT, bk, bv, KFp, VFp);

  // Q projection (bf16 A), pre-scaled by 1/sqrt(dk)*log2(e)
  gemm_bf16_kernel<0><<<dim3(M_ / 128, DM / 64), 256, 0, stream>>>(
      Xqbf, WqT, bq, Qbf, M_, DM, DM, 0.125f * 1.44269504088896f);

  attn_kernel<<<dim3(64, H_, B_), 256, 0, stream>>>(Qbf, KFp, VFp, AObf);

  gemm_bf16_kernel<1><<<dim3(M_ / 128, DM / 64), 256, 0, stream>>>(
      AObf, WoT, bo, d_out, M_, DM, DM, 1.0f);
}

// Round 21
// 117.009 us; speedup vs baseline: 1.0488x; 1.0002x over previous
//
#include <hip/hip_runtime.h>
#include <cstdint>
#include <cstddef>

typedef unsigned short u16;
typedef __bf16 bf16x8 __attribute__((ext_vector_type(8)));
typedef float  f32x4  __attribute__((ext_vector_type(4)));
typedef float  f32x16 __attribute__((ext_vector_type(16)));
typedef unsigned u32x4 __attribute__((ext_vector_type(4)));

#define DEV __device__ __forceinline__

#define B_  2
#define S_  2048
#define DM  1024
#define H_  16
#define DK  64
#define M_  (B_ * S_)   // 4096

#if __has_builtin(__builtin_amdgcn_exp2f)
#define EXP2(x) __builtin_amdgcn_exp2f(x)
#else
#define EXP2(x) exp2f(x)
#endif

// ---------------- workspace layout (bytes) ----------------
constexpr size_t OFF_QBF  = 0;                                  // Q proj out bf16 [M][DM]
constexpr size_t OFF_KF   = OFF_QBF  + (size_t)M_ * DM * 2;     // K frag-linear (sigma rows)
constexpr size_t OFF_VF   = OFF_KF   + (size_t)M_ * DK * 2;     // V frag-linear
constexpr size_t OFF_AOBF = OFF_VF   + (size_t)M_ * DK * 2;     // attn out bf16 [M][DM]
constexpr size_t OFF_WQT  = OFF_AOBF + (size_t)M_ * DM * 2;     // Wq^T bf16 [DM][DM]
constexpr size_t OFF_WOT  = OFF_WQT  + (size_t)DM * DM * 2;     // Wo^T bf16 [DM][DM]
constexpr size_t OFF_WKT  = OFF_WOT  + (size_t)DM * DM * 2;     // Wk^T bf16 [DK][DM]
constexpr size_t OFF_WVT  = OFF_WKT  + (size_t)DK * DM * 2;     // Wv^T bf16 [DK][DM]
constexpr size_t OFF_XQBF = OFF_WVT  + (size_t)DK * DM * 2;     // inputs_q bf16 [M][DM]

// ---------------- helpers ----------------
DEV u16 f2bf(float f) {                 // RNE f32 -> bf16
  unsigned u = __float_as_uint(f);
  u += 0x7fffu + ((u >> 16) & 1u);
  return (u16)(u >> 16);
}

DEV unsigned cvtpk(float lo, float hi) { // pack 2 f32 -> 2 bf16 (lo in low 16)
  return (unsigned)f2bf(lo) | ((unsigned)f2bf(hi) << 16);
}

DEV unsigned cvtpk_hw(float lo, float hi) { // v_cvt_pk_bf16_f32 (1 instr)
  unsigned r;
  asm("v_cvt_pk_bf16_f32 %0, %1, %2" : "=v"(r) : "v"(lo), "v"(hi));
  return r;
}

DEV u32x4 pack8(const float4& a, const float4& b) {
  u32x4 w;
  w[0] = cvtpk(a.x, a.y);
  w[1] = cvtpk(a.z, a.w);
  w[2] = cvtpk(b.x, b.y);
  w[3] = cvtpk(b.z, b.w);
  return w;
}

DEV void gload_lds16(const void* g, void* l) {
  __builtin_amdgcn_global_load_lds(
      (const __attribute__((address_space(1))) unsigned int*)g,
      (__attribute__((address_space(3))) unsigned int*)l, 16, 0, 0);
}

// ---------------- cast f32 -> bf16, 8 elems/thread ----------------
__global__ __launch_bounds__(256) void cast_bf16_kernel(
    const float* __restrict__ in, u16* __restrict__ out, int n8) {
  const int stride = gridDim.x * blockDim.x;
  for (int i = blockIdx.x * blockDim.x + threadIdx.x; i < n8; i += stride) {
    float4 a = ((const float4*)in)[2 * i];
    float4 b = ((const float4*)in)[2 * i + 1];
    ((u32x4*)out)[i] = pack8(a, b);
  }
}

// ---------------- transpose + cast W[R][C] f32 -> WT[C][R] bf16 ----------------
__global__ void transpose_cast_kernel(const float* __restrict__ W,
                                      u16* __restrict__ WT, int R, int C) {
  __shared__ u16 tile[32][33];
  const int c0 = blockIdx.x * 32, r0 = blockIdx.y * 32;
  for (int i = threadIdx.y; i < 32; i += 8)
    tile[i][threadIdx.x] = f2bf(W[(size_t)(r0 + i) * C + c0 + threadIdx.x]);
  __syncthreads();
  for (int i = threadIdx.y; i < 32; i += 8)
    WT[(size_t)(c0 + i) * R + r0 + threadIdx.x] = tile[threadIdx.x][i];
}

// ---------------- K/V projection via MFMA, f32 input, fused fragment-linear emit ----------------
__global__ __launch_bounds__(256) void kvproj_kernel(
    const float* __restrict__ Xk, const float* __restrict__ Xv,
    const u16* __restrict__ WkT, const u16* __restrict__ WvT,
    const float* __restrict__ bk, const float* __restrict__ bv,
    u16* __restrict__ KF, u16* __restrict__ VF) {
  __shared__ __align__(16) u16 At[64 * 32];
  __shared__ __align__(16) u16 Bt[64 * 32];
  __shared__ u16 stage[64][72];
  const int sel = blockIdx.y;
  const float* X = sel ? Xv : Xk;
  const u16* WT = sel ? WvT : WkT;
  const float* bias = sel ? bv : bk;

  const int tid = threadIdx.x, wave = tid >> 6, lane = tid & 63;
  const int g = lane >> 4, c = lane & 15;
  const int wm = wave >> 1, wn = wave & 1;
  const int bm = blockIdx.x;
  f32x4 acc[2][2] = {};

  const int row = tid >> 2, sd = tid & 3;
  const float* Asrc = X + (size_t)(bm * 64 + row) * DM + sd * 8;
  const u16* Bsrc = WT + (size_t)row * DM + ((sd ^ (row & 3)) * 8);
  u16* Adst = At + row * 32 + ((sd ^ (row & 3)) * 8);   // write-side swizzle

  for (int k0 = 0; k0 < DM; k0 += 32) {
    __syncthreads();
    const float4 x0 = *(const float4*)(Asrc + k0);
    const float4 x1 = *(const float4*)(Asrc + k0 + 4);
    gload_lds16(Bsrc + k0, Bt + wave * 512);
    *(u32x4*)Adst = pack8(x0, x1);
    asm volatile("s_waitcnt vmcnt(0)" ::: "memory");
    __syncthreads();

    bf16x8 af[2], bfr[2];
#pragma unroll
    for (int mf = 0; mf < 2; ++mf) {
      const int ra = wm * 32 + mf * 16 + c;
      af[mf] = *(const bf16x8*)(At + ra * 32 + ((g ^ (ra & 3)) * 8));
    }
#pragma unroll
    for (int nf = 0; nf < 2; ++nf) {
      const int rb = wn * 32 + nf * 16 + c;
      bfr[nf] = *(const bf16x8*)(Bt + rb * 32 + ((g ^ (rb & 3)) * 8));
    }
#pragma unroll
    for (int mf = 0; mf < 2; ++mf)
#pragma unroll
      for (int nf = 0; nf < 2; ++nf)
        acc[mf][nf] = __builtin_amdgcn_mfma_f32_16x16x32_bf16(
            af[mf], bfr[nf], acc[mf][nf], 0, 0, 0);
  }

  // stage D-layout output (bias added) into LDS
  __syncthreads();
#pragma unroll
  for (int nf = 0; nf < 2; ++nf) {
    const int col = wn * 32 + nf * 16 + c;
    const float bs = bias[col];
#pragma unroll
    for (int mf = 0; mf < 2; ++mf)
#pragma unroll
      for (int r = 0; r < 4; ++r)
        stage[wm * 32 + mf * 16 + g * 4 + r][col] = f2bf(acc[mf][nf][r] + bs);
  }
  __syncthreads();

  // fragment-linear emit (same mapping as the proven repack kernel)
  u16* outF = (sel ? VF : KF) + (size_t)bm * 4096;
#pragma unroll
  for (int p = 0; p < 2; ++p) {
    const int id = tid + p * 256;          // (sub,ks,lane)
    const int sub = id >> 8, ks = (id >> 6) & 3, ln = id & 63;
    const int hi2 = ln >> 5, q = ln & 31;
    if (!sel) {   // K: sigma = swap bits 2<->3 of q
      const int sq = (q & ~12) | ((q & 4) << 1) | ((q & 8) >> 1);
      *(bf16x8*)&outF[id * 8] = *(const bf16x8*)&stage[sub * 32 + sq][ks * 16 + hi2 * 8];
    } else {      // V: transposed
      u16 tmp[8];
#pragma unroll
      for (int i = 0; i < 8; ++i)
        tmp[i] = stage[ks * 16 + hi2 * 8 + i][sub * 32 + q];
      *(bf16x8*)&outF[id * 8] = *(const bf16x8*)tmp;
    }
  }
}

// ---------------- 2-phase double-buffered 128x64 bf16 GEMM, BK=64 ----------------
template <int OUT_F32>
__global__ __launch_bounds__(256) void gemm_bf16_kernel(
    const u16* __restrict__ A, const u16* __restrict__ BT,
    const float* __restrict__ bias, void* __restrict__ Cout,
    int M, int N, int K, float oscale) {
  __shared__ __align__(16) u16 At[2][128 * 64];   // 16 KB / buf
  __shared__ __align__(16) u16 Bt[2][64 * 64];    //  8 KB / buf
  const int tid = threadIdx.x, wave = tid >> 6, lane = tid & 63;
  const int bm = blockIdx.x, bn = blockIdx.y;
  const int wm = wave >> 1, wn = wave & 1;
  const int g = lane >> 4, c = lane & 15;
  f32x4 acc[4][2] = {};

  // staging maps (16B bf16 slots, source col pre-swizzled; linear LDS dest)
  int arow[4], acol[4], brow[2], bcol[2];
#pragma unroll
  for (int i = 0; i < 4; ++i) {
    const int sid = (i * 4 + wave) * 64 + lane;   // 0..1023
    arow[i] = sid >> 3;
    acol[i] = ((sid & 7) ^ ((sid >> 3) & 7)) * 8;
  }
#pragma unroll
  for (int i = 0; i < 2; ++i) {
    const int sid = (i * 4 + wave) * 64 + lane;   // 0..511
    brow[i] = sid >> 3;
    bcol[i] = ((sid & 7) ^ ((sid >> 3) & 7)) * 8;
  }
  const int nt = K >> 6;

  auto stage_g = [&](int buf, int t) {
    const int k0_ = t << 6;
#pragma unroll
    for (int i = 0; i < 4; ++i)
      gload_lds16(A + (size_t)(bm * 128 + arow[i]) * K + k0_ + acol[i],
                  &At[buf][(i * 4 + wave) * 512]);
#pragma unroll
    for (int i = 0; i < 2; ++i)
      gload_lds16(BT + (size_t)(bn * 64 + brow[i]) * K + k0_ + bcol[i],
                  &Bt[buf][(i * 4 + wave) * 512]);
  };

  stage_g(0, 0);
  asm volatile("s_waitcnt vmcnt(0)" ::: "memory");
  __syncthreads();

  int cur = 0;
  for (int t = 0; t < nt; ++t) {
    if (t + 1 < nt) stage_g(cur ^ 1, t + 1);   // issue next-tile loads FIRST
#pragma unroll
    for (int kk = 0; kk < 2; ++kk) {
      bf16x8 af[4], bfr[2];
#pragma unroll
      for (int mf = 0; mf < 4; ++mf) {
        const int row = wm * 64 + mf * 16 + c;
        af[mf] = *(const bf16x8*)(&At[cur][row * 64 + ((kk * 4 + g) ^ (row & 7)) * 8]);
      }
#pragma unroll
      for (int nf = 0; nf < 2; ++nf) {
        const int row = wn * 32 + nf * 16 + c;
        bfr[nf] = *(const bf16x8*)(&Bt[cur][row * 64 + ((kk * 4 + g) ^ (row & 7)) * 8]);
      }
#pragma unroll
      for (int mf = 0; mf < 4; ++mf)
#pragma unroll
        for (int nf = 0; nf < 2; ++nf)
          acc[mf][nf] = __builtin_amdgcn_mfma_f32_16x16x32_bf16(
              af[mf], bfr[nf], acc[mf][nf], 0, 0, 0);
    }
    asm volatile("s_waitcnt vmcnt(0)" ::: "memory");  // next tile landed
    __syncthreads();
    cur ^= 1;
  }

  const int colb = bn * 64 + wn * 32 + c;
  const int rowb = bm * 128 + wm * 64 + g * 4;
#pragma unroll
  for (int nf = 0; nf < 2; ++nf) {
    float bs = bias[colb + nf * 16];
#pragma unroll
    for (int mf = 0; mf < 4; ++mf) {
#pragma unroll
      for (int r = 0; r < 4; ++r) {
        size_t idx = (size_t)(rowb + mf * 16 + r) * N + colb + nf * 16;
        float v = (acc[mf][nf][r] + bs) * oscale;
        if (OUT_F32) ((float*)Cout)[idx] = v;
        else         ((u16*)Cout)[idx]   = f2bf(v);
      }
    }
  }
}

// ---------------- attn: per-tile load / compute building blocks (R14 proven) ----------------
DEV void attn_load(const u16* kp, const u16* vp, bf16x8* kf, bf16x8* vf) {
#pragma unroll
  for (int i = 0; i < 4; ++i) {
    kf[i]     = *(const bf16x8*)(kp + i * 512);
    kf[4 + i] = *(const bf16x8*)(kp + 2048 + i * 512);
    vf[i]     = *(const bf16x8*)(vp + i * 512);
    vf[4 + i] = *(const bf16x8*)(vp + 2048 + i * 512);
  }
}

DEV void attn_comp(int t, int qrow, int hi, bool evenU, int nt,
                   const bf16x8* kf, const bf16x8* vf, const bf16x8* qf,
                   f32x16& acc0, f32x16& acc1, float& l_) {
  const int kv0 = t * 64;
  const bool diag = (t == nt - 1);
  const bool skipHi = diag && evenU;

  f32x16 sf0 = {}, sf1 = {};
  __builtin_amdgcn_s_setprio(1);
#pragma unroll
  for (int ks = 0; ks < 4; ++ks)
    sf0 = __builtin_amdgcn_mfma_f32_32x32x16_bf16(kf[ks], qf[ks], sf0, 0, 0, 0);
  if (!skipHi) {
#pragma unroll
    for (int ks = 0; ks < 4; ++ks)
      sf1 = __builtin_amdgcn_mfma_f32_32x32x16_bf16(kf[4 + ks], qf[ks], sf1, 0, 0, 0);
  }
  __builtin_amdgcn_s_setprio(0);

  if (diag) {   // causal mask; kv of reg r = 16*(r>>3) + 8*hi + (r&7)
#pragma unroll
    for (int r = 0; r < 16; ++r) {
      const int kvl = (r & 7) + 8 * hi + 16 * (r >> 3);
      if (kv0 + kvl > qrow)      sf0[r] = -1e30f;
      if (kv0 + 32 + kvl > qrow) sf1[r] = -1e30f;
    }
  }

  float rs0 = 0.f, rs1 = 0.f;
#pragma unroll
  for (int r = 0; r < 8; ++r)  { float e = EXP2(sf0[r]); sf0[r] = e; rs0 += e; }
#pragma unroll
  for (int r = 8; r < 16; ++r) { float e = EXP2(sf0[r]); sf0[r] = e; rs1 += e; }
  if (!skipHi) {
#pragma unroll
    for (int r = 0; r < 8; ++r)  { float e = EXP2(sf1[r]); sf1[r] = e; rs0 += e; }
#pragma unroll
    for (int r = 8; r < 16; ++r) { float e = EXP2(sf1[r]); sf1[r] = e; rs1 += e; }
  }
  l_ += rs0 + rs1;

  __builtin_amdgcn_s_setprio(1);
#pragma unroll
  for (int at = 0; at < 2; ++at) {
    if (at == 1 && skipHi) break;
    const f32x16& sfv = at ? sf1 : sf0;
#pragma unroll
    for (int half = 0; half < 2; ++half) {
      const int rb = half * 8;
      u32x4 pw;
      pw[0] = cvtpk_hw(sfv[rb + 0], sfv[rb + 1]);
      pw[1] = cvtpk_hw(sfv[rb + 2], sfv[rb + 3]);
      pw[2] = cvtpk_hw(sfv[rb + 4], sfv[rb + 5]);
      pw[3] = cvtpk_hw(sfv[rb + 6], sfv[rb + 7]);
      const bf16x8 pa = __builtin_bit_cast(bf16x8, pw);
      const int ksg = at * 2 + half;
      acc0 = __builtin_amdgcn_mfma_f32_32x32x16_bf16(pa, vf[ksg], acc0, 0, 0, 0);
      acc1 = __builtin_amdgcn_mfma_f32_32x32x16_bf16(pa, vf[4 + ksg], acc1, 0, 0, 0);
    }
  }
  __builtin_amdgcn_s_setprio(0);
}

// ---------------- causal MQA flash attention: split-KV, 2-wave blocks, LPT ----------------
// grid (64, H, B), block 128 = 2 waves; wave w owns kv tiles t = w, w+2, ...
// LDS 16.5 KB/block -> ~9 blocks/CU resident (vs 4 at W=4): doubles achievable
// TLP for this latency-bound kernel. Ping-pong fragment buffers as in R14.
__global__ __launch_bounds__(128, 2) void attn_kernel(
    const u16* __restrict__ Q,   // [B*S][DM] bf16 (head h at col h*64), pre-scaled
    const u16* __restrict__ KF,  // fragment-linear K (sigma-permuted rows)
    const u16* __restrict__ VF,  // fragment-linear V
    u16* __restrict__ O) {       // [B*S][DM] bf16
  __shared__ float Ll[2][32];
  __shared__ float Lacc[2][32][64];   // 16 KB

  const int j = blockIdx.x, h = blockIdx.y, b = blockIdx.z;
  const int wave = threadIdx.x >> 6, lane = threadIdx.x & 63;
  const int q31 = lane & 31, hi = lane >> 5;

  const int u = 63 - j;                  // LPT order
  const int qrow = u * 32 + q31;
  const int nt = (u + 2) >> 1;           // kv tiles for this q-unit
  const bool evenU = !(u & 1);

  const u16* Qp = Q + (size_t)(b * S_ + qrow) * DM + h * DK;
  bf16x8 qf[4];
#pragma unroll
  for (int ks = 0; ks < 4; ++ks)
    qf[ks] = *(const bf16x8*)(Qp + ks * 16 + hi * 8);

  f32x16 acc0 = {}, acc1 = {};
  float l_ = 0.f;

  const u16* kfb = KF + (size_t)(b * 32) * 4096 + lane * 8;
  const u16* vfb = VF + (size_t)(b * 32) * 4096 + lane * 8;

  bf16x8 kA[8], vA[8], kB[8], vB[8];
  int t = wave;
  if (t < nt)
    attn_load(kfb + (size_t)t * 4096, vfb + (size_t)t * 4096, kA, vA);
  for (; t < nt; t += 4) {
    const int t1 = t + 2;
    if (t1 < nt)
      attn_load(kfb + (size_t)t1 * 4096, vfb + (size_t)t1 * 4096, kB, vB);
    attn_comp(t, qrow, hi, evenU, nt, kA, vA, qf, acc0, acc1, l_);
    if (t1 < nt) {
      const int t2 = t1 + 2;
      if (t2 < nt)
        attn_load(kfb + (size_t)t2 * 4096, vfb + (size_t)t2 * 4096, kA, vA);
      attn_comp(t1, qrow, hi, evenU, nt, kB, vB, qf, acc0, acc1, l_);
    }
  }

  // one lane^32 combine of the per-lane l partials
  l_ += __shfl_xor(l_, 32);

  // ---- block-level combine of the 2 partials (plain sums) ----
  if (hi == 0) Ll[wave][q31] = l_;
  __syncthreads();

#pragma unroll
  for (int r = 0; r < 16; ++r) {
    const int rr = (r & 3) + 8 * (r >> 2) + 4 * hi;   // acc row (PV D layout)
    Lacc[wave][rr][q31]      = acc0[r];
    Lacc[wave][rr][32 + q31] = acc1[r];
  }
  __syncthreads();

  // 128 threads: row = tid>>2 (32 rows), dv0 = (tid&3)*16, 16 elems each
  const int tid = threadIdx.x;
  const int row = tid >> 2;
  const int dv0 = (tid & 3) * 16;
  const float Lr = Ll[0][row] + Ll[1][row];
  const float linv = 1.f / Lr;
  u16 ov[16];
#pragma unroll
  for (int i = 0; i < 16; ++i) {
    const float v = (Lacc[0][row][dv0 + i] + Lacc[1][row][dv0 + i]) * linv;
    ov[i] = f2bf(v);
  }
  u16* Op = O + (size_t)(b * S_ + u * 32 + row) * DM + h * DK + dv0;
  *(bf16x8*)Op       = *(const bf16x8*)ov;
  *(bf16x8*)(Op + 8) = *(const bf16x8*)(ov + 8);
}

// ---------------- launch ----------------
extern "C" void kernel_launch(void* const* d_in, const int* in_sizes, int n_in,
                              void* d_out, int out_size, void* d_ws, size_t ws_size,
                              hipStream_t stream) {
  const float* in_q = (const float*)d_in[0];
  const float* in_k = (const float*)d_in[1];
  const float* in_v = (const float*)d_in[2];
  const float* Wq   = (const float*)d_in[3];
  const float* bq   = (const float*)d_in[4];
  const float* Wk   = (const float*)d_in[5];
  const float* bk   = (const float*)d_in[6];
  const float* Wv   = (const float*)d_in[7];
  const float* bv   = (const float*)d_in[8];
  const float* Wo   = (const float*)d_in[9];
  const float* bo   = (const float*)d_in[10];

  char* ws  = (char*)d_ws;
  u16* Qbf  = (u16*)(ws + OFF_QBF);
  u16* KFp  = (u16*)(ws + OFF_KF);
  u16* VFp  = (u16*)(ws + OFF_VF);
  u16* AObf = (u16*)(ws + OFF_AOBF);
  u16* WqT  = (u16*)(ws + OFF_WQT);
  u16* WoT  = (u16*)(ws + OFF_WOT);
  u16* WkT  = (u16*)(ws + OFF_WKT);
  u16* WvT  = (u16*)(ws + OFF_WVT);
  u16* Xqbf = (u16*)(ws + OFF_XQBF);

  cast_bf16_kernel<<<2048, 256, 0, stream>>>(in_q, Xqbf, M_ * DM / 8);

  transpose_cast_kernel<<<dim3(32, 32), dim3(32, 8), 0, stream>>>(Wq, WqT, DM, DM);
  transpose_cast_kernel<<<dim3(32, 32), dim3(32, 8), 0, stream>>>(Wo, WoT, DM, DM);
  transpose_cast_kernel<<<dim3(2, 32),  dim3(32, 8), 0, stream>>>(Wk, WkT, DM, DK);
  transpose_cast_kernel<<<dim3(2, 32),  dim3(32, 8), 0, stream>>>(Wv, WvT, DM, DK);

  // K/V projection reading f32 inputs directly (cast fused into staging)
  kvproj_kernel<<<dim3(M_ / 64, 2), 256, 0, stream>>>(
      in_k, in_v, WkT, WvT, bk, bv, KFp, VFp);

  // Q projection (bf16 A), pre-scaled by 1/sqrt(dk)*log2(e)
  gemm_bf16_kernel<0><<<dim3(M_ / 128, DM / 64), 256, 0, stream>>>(
      Xqbf, WqT, bq, Qbf, M_, DM, DM, 0.125f * 1.44269504088896f);

  attn_kernel<<<dim3(64, H_, B_), 128, 0, stream>>>(Qbf, KFp, VFp, AObf);

  gemm_bf16_kernel<1><<<dim3(M_ / 128, DM / 64), 256, 0, stream>>>(
      AObf, WoT, bo, d_out, M_, DM, DM, 1.0f);
}

// Round 22
// 108.336 us; speedup vs baseline: 1.1327x; 1.0801x over previous
//
#include <hip/hip_runtime.h>
#include <cstdint>
#include <cstddef>

typedef unsigned short u16;
typedef __bf16 bf16x8 __attribute__((ext_vector_type(8)));
typedef float  f32x4  __attribute__((ext_vector_type(4)));
typedef float  f32x16 __attribute__((ext_vector_type(16)));
typedef unsigned u32x4 __attribute__((ext_vector_type(4)));

#define DEV __device__ __forceinline__

#define B_  2
#define S_  2048
#define DM  1024
#define H_  16
#define DK  64
#define M_  (B_ * S_)   // 4096

#if __has_builtin(__builtin_amdgcn_exp2f)
#define EXP2(x) __builtin_amdgcn_exp2f(x)
#else
#define EXP2(x) exp2f(x)
#endif

// ---------------- workspace layout (bytes) ----------------
constexpr size_t OFF_QBF  = 0;                                  // Q proj out bf16 [M][DM]
constexpr size_t OFF_KF   = OFF_QBF  + (size_t)M_ * DM * 2;     // K frag-linear (sigma rows)
constexpr size_t OFF_VF   = OFF_KF   + (size_t)M_ * DK * 2;     // V frag-linear
constexpr size_t OFF_AOBF = OFF_VF   + (size_t)M_ * DK * 2;     // attn out bf16 [M][DM]
constexpr size_t OFF_WQT  = OFF_AOBF + (size_t)M_ * DM * 2;     // Wq^T bf16 [DM][DM]
constexpr size_t OFF_WOT  = OFF_WQT  + (size_t)DM * DM * 2;     // Wo^T bf16 [DM][DM]
constexpr size_t OFF_WKT  = OFF_WOT  + (size_t)DM * DM * 2;     // Wk^T bf16 [DK][DM]
constexpr size_t OFF_WVT  = OFF_WKT  + (size_t)DK * DM * 2;     // Wv^T bf16 [DK][DM]
constexpr size_t OFF_XQBF = OFF_WVT  + (size_t)DK * DM * 2;     // inputs_q bf16 [M][DM]

// ---------------- helpers ----------------
DEV u16 f2bf(float f) {                 // RNE f32 -> bf16
  unsigned u = __float_as_uint(f);
  u += 0x7fffu + ((u >> 16) & 1u);
  return (u16)(u >> 16);
}

DEV unsigned cvtpk(float lo, float hi) { // pack 2 f32 -> 2 bf16 (lo in low 16)
  return (unsigned)f2bf(lo) | ((unsigned)f2bf(hi) << 16);
}

DEV unsigned cvtpk_hw(float lo, float hi) { // v_cvt_pk_bf16_f32 (1 instr)
  unsigned r;
  asm("v_cvt_pk_bf16_f32 %0, %1, %2" : "=v"(r) : "v"(lo), "v"(hi));
  return r;
}

DEV u32x4 pack8(const float4& a, const float4& b) {
  u32x4 w;
  w[0] = cvtpk(a.x, a.y);
  w[1] = cvtpk(a.z, a.w);
  w[2] = cvtpk(b.x, b.y);
  w[3] = cvtpk(b.z, b.w);
  return w;
}

DEV void gload_lds16(const void* g, void* l) {
  __builtin_amdgcn_global_load_lds(
      (const __attribute__((address_space(1))) unsigned int*)g,
      (__attribute__((address_space(3))) unsigned int*)l, 16, 0, 0);
}

// ---------------- merged prep: 4 weight transposes + in_q cast, one launch ----------------
// grid (32, 32, 5), block (32, 8). z=0..3: transpose+cast Wq/Wo/Wk/Wv;
// z=4: cast in_q f32->bf16 (grid-stride over 1024*256 threads).
__global__ __launch_bounds__(256) void prep_kernel(
    const float* __restrict__ Wq, const float* __restrict__ Wo,
    const float* __restrict__ Wk, const float* __restrict__ Wv,
    const float* __restrict__ in_q,
    u16* __restrict__ WqT, u16* __restrict__ WoT,
    u16* __restrict__ WkT, u16* __restrict__ WvT,
    u16* __restrict__ Xq) {
  const int z = blockIdx.z;
  if (z == 4) {                        // cast in_q: 4M f32 -> bf16
    const int tid = (blockIdx.y * 32 + blockIdx.x) * 256 +
                    threadIdx.y * 32 + threadIdx.x;
    const int n8 = M_ * DM / 8;
    for (int i = tid; i < n8; i += 1024 * 256) {
      float4 a = ((const float4*)in_q)[2 * i];
      float4 b = ((const float4*)in_q)[2 * i + 1];
      ((u32x4*)Xq)[i] = pack8(a, b);
    }
    return;
  }
  const float* W; u16* WT; int C;
  if (z == 0)      { W = Wq; WT = WqT; C = DM; }
  else if (z == 1) { W = Wo; WT = WoT; C = DM; }
  else if (z == 2) { W = Wk; WT = WkT; C = DK; }
  else             { W = Wv; WT = WvT; C = DK; }
  const int c0 = blockIdx.x * 32, r0 = blockIdx.y * 32;
  if (c0 >= C) return;                 // block-uniform exit (Wk/Wv: only x<2)
  __shared__ u16 tile[32][33];
  for (int i = threadIdx.y; i < 32; i += 8)
    tile[i][threadIdx.x] = f2bf(W[(size_t)(r0 + i) * C + c0 + threadIdx.x]);
  __syncthreads();
  for (int i = threadIdx.y; i < 32; i += 8)
    WT[(size_t)(c0 + i) * DM + r0 + threadIdx.x] = tile[threadIdx.x][i];
}

// ---------------- K/V projection via MFMA, f32 input, fused fragment-linear emit ----------------
__global__ __launch_bounds__(256) void kvproj_kernel(
    const float* __restrict__ Xk, const float* __restrict__ Xv,
    const u16* __restrict__ WkT, const u16* __restrict__ WvT,
    const float* __restrict__ bk, const float* __restrict__ bv,
    u16* __restrict__ KF, u16* __restrict__ VF) {
  __shared__ __align__(16) u16 At[64 * 32];
  __shared__ __align__(16) u16 Bt[64 * 32];
  __shared__ u16 stage[64][72];
  const int sel = blockIdx.y;
  const float* X = sel ? Xv : Xk;
  const u16* WT = sel ? WvT : WkT;
  const float* bias = sel ? bv : bk;

  const int tid = threadIdx.x, wave = tid >> 6, lane = tid & 63;
  const int g = lane >> 4, c = lane & 15;
  const int wm = wave >> 1, wn = wave & 1;
  const int bm = blockIdx.x;
  f32x4 acc[2][2] = {};

  const int row = tid >> 2, sd = tid & 3;
  const float* Asrc = X + (size_t)(bm * 64 + row) * DM + sd * 8;
  const u16* Bsrc = WT + (size_t)row * DM + ((sd ^ (row & 3)) * 8);
  u16* Adst = At + row * 32 + ((sd ^ (row & 3)) * 8);   // write-side swizzle

  for (int k0 = 0; k0 < DM; k0 += 32) {
    __syncthreads();
    const float4 x0 = *(const float4*)(Asrc + k0);
    const float4 x1 = *(const float4*)(Asrc + k0 + 4);
    gload_lds16(Bsrc + k0, Bt + wave * 512);
    *(u32x4*)Adst = pack8(x0, x1);
    asm volatile("s_waitcnt vmcnt(0)" ::: "memory");
    __syncthreads();

    bf16x8 af[2], bfr[2];
#pragma unroll
    for (int mf = 0; mf < 2; ++mf) {
      const int ra = wm * 32 + mf * 16 + c;
      af[mf] = *(const bf16x8*)(At + ra * 32 + ((g ^ (ra & 3)) * 8));
    }
#pragma unroll
    for (int nf = 0; nf < 2; ++nf) {
      const int rb = wn * 32 + nf * 16 + c;
      bfr[nf] = *(const bf16x8*)(Bt + rb * 32 + ((g ^ (rb & 3)) * 8));
    }
#pragma unroll
    for (int mf = 0; mf < 2; ++mf)
#pragma unroll
      for (int nf = 0; nf < 2; ++nf)
        acc[mf][nf] = __builtin_amdgcn_mfma_f32_16x16x32_bf16(
            af[mf], bfr[nf], acc[mf][nf], 0, 0, 0);
  }

  // stage D-layout output (bias added) into LDS
  __syncthreads();
#pragma unroll
  for (int nf = 0; nf < 2; ++nf) {
    const int col = wn * 32 + nf * 16 + c;
    const float bs = bias[col];
#pragma unroll
    for (int mf = 0; mf < 2; ++mf)
#pragma unroll
      for (int r = 0; r < 4; ++r)
        stage[wm * 32 + mf * 16 + g * 4 + r][col] = f2bf(acc[mf][nf][r] + bs);
  }
  __syncthreads();

  // fragment-linear emit (same mapping as the proven repack kernel)
  u16* outF = (sel ? VF : KF) + (size_t)bm * 4096;
#pragma unroll
  for (int p = 0; p < 2; ++p) {
    const int id = tid + p * 256;          // (sub,ks,lane)
    const int sub = id >> 8, ks = (id >> 6) & 3, ln = id & 63;
    const int hi2 = ln >> 5, q = ln & 31;
    if (!sel) {   // K: sigma = swap bits 2<->3 of q
      const int sq = (q & ~12) | ((q & 4) << 1) | ((q & 8) >> 1);
      *(bf16x8*)&outF[id * 8] = *(const bf16x8*)&stage[sub * 32 + sq][ks * 16 + hi2 * 8];
    } else {      // V: transposed
      u16 tmp[8];
#pragma unroll
      for (int i = 0; i < 8; ++i)
        tmp[i] = stage[ks * 16 + hi2 * 8 + i][sub * 32 + q];
      *(bf16x8*)&outF[id * 8] = *(const bf16x8*)tmp;
    }
  }
}

// ---------------- 2-phase double-buffered 128x64 bf16 GEMM, BK=64 ----------------
template <int OUT_F32>
__global__ __launch_bounds__(256) void gemm_bf16_kernel(
    const u16* __restrict__ A, const u16* __restrict__ BT,
    const float* __restrict__ bias, void* __restrict__ Cout,
    int M, int N, int K, float oscale) {
  __shared__ __align__(16) u16 At[2][128 * 64];   // 16 KB / buf
  __shared__ __align__(16) u16 Bt[2][64 * 64];    //  8 KB / buf
  const int tid = threadIdx.x, wave = tid >> 6, lane = tid & 63;
  const int bm = blockIdx.x, bn = blockIdx.y;
  const int wm = wave >> 1, wn = wave & 1;
  const int g = lane >> 4, c = lane & 15;
  f32x4 acc[4][2] = {};

  // staging maps (16B bf16 slots, source col pre-swizzled; linear LDS dest)
  int arow[4], acol[4], brow[2], bcol[2];
#pragma unroll
  for (int i = 0; i < 4; ++i) {
    const int sid = (i * 4 + wave) * 64 + lane;   // 0..1023
    arow[i] = sid >> 3;
    acol[i] = ((sid & 7) ^ ((sid >> 3) & 7)) * 8;
  }
#pragma unroll
  for (int i = 0; i < 2; ++i) {
    const int sid = (i * 4 + wave) * 64 + lane;   // 0..511
    brow[i] = sid >> 3;
    bcol[i] = ((sid & 7) ^ ((sid >> 3) & 7)) * 8;
  }
  const int nt = K >> 6;

  auto stage_g = [&](int buf, int t) {
    const int k0_ = t << 6;
#pragma unroll
    for (int i = 0; i < 4; ++i)
      gload_lds16(A + (size_t)(bm * 128 + arow[i]) * K + k0_ + acol[i],
                  &At[buf][(i * 4 + wave) * 512]);
#pragma unroll
    for (int i = 0; i < 2; ++i)
      gload_lds16(BT + (size_t)(bn * 64 + brow[i]) * K + k0_ + bcol[i],
                  &Bt[buf][(i * 4 + wave) * 512]);
  };

  stage_g(0, 0);
  asm volatile("s_waitcnt vmcnt(0)" ::: "memory");
  __syncthreads();

  int cur = 0;
  for (int t = 0; t < nt; ++t) {
    if (t + 1 < nt) stage_g(cur ^ 1, t + 1);   // issue next-tile loads FIRST
#pragma unroll
    for (int kk = 0; kk < 2; ++kk) {
      bf16x8 af[4], bfr[2];
#pragma unroll
      for (int mf = 0; mf < 4; ++mf) {
        const int row = wm * 64 + mf * 16 + c;
        af[mf] = *(const bf16x8*)(&At[cur][row * 64 + ((kk * 4 + g) ^ (row & 7)) * 8]);
      }
#pragma unroll
      for (int nf = 0; nf < 2; ++nf) {
        const int row = wn * 32 + nf * 16 + c;
        bfr[nf] = *(const bf16x8*)(&Bt[cur][row * 64 + ((kk * 4 + g) ^ (row & 7)) * 8]);
      }
#pragma unroll
      for (int mf = 0; mf < 4; ++mf)
#pragma unroll
        for (int nf = 0; nf < 2; ++nf)
          acc[mf][nf] = __builtin_amdgcn_mfma_f32_16x16x32_bf16(
              af[mf], bfr[nf], acc[mf][nf], 0, 0, 0);
    }
    asm volatile("s_waitcnt vmcnt(0)" ::: "memory");  // next tile landed
    __syncthreads();
    cur ^= 1;
  }

  const int colb = bn * 64 + wn * 32 + c;
  const int rowb = bm * 128 + wm * 64 + g * 4;
#pragma unroll
  for (int nf = 0; nf < 2; ++nf) {
    float bs = bias[colb + nf * 16];
#pragma unroll
    for (int mf = 0; mf < 4; ++mf) {
#pragma unroll
      for (int r = 0; r < 4; ++r) {
        size_t idx = (size_t)(rowb + mf * 16 + r) * N + colb + nf * 16;
        float v = (acc[mf][nf][r] + bs) * oscale;
        if (OUT_F32) ((float*)Cout)[idx] = v;
        else         ((u16*)Cout)[idx]   = f2bf(v);
      }
    }
  }
}

// ---------------- attn: per-tile load / compute building blocks (R14 proven) ----------------
DEV void attn_load(const u16* kp, const u16* vp, bf16x8* kf, bf16x8* vf) {
#pragma unroll
  for (int i = 0; i < 4; ++i) {
    kf[i]     = *(const bf16x8*)(kp + i * 512);
    kf[4 + i] = *(const bf16x8*)(kp + 2048 + i * 512);
    vf[i]     = *(const bf16x8*)(vp + i * 512);
    vf[4 + i] = *(const bf16x8*)(vp + 2048 + i * 512);
  }
}

DEV void attn_comp(int t, int qrow, int hi, bool evenU, int nt,
                   const bf16x8* kf, const bf16x8* vf, const bf16x8* qf,
                   f32x16& acc0, f32x16& acc1, float& l_) {
  const int kv0 = t * 64;
  const bool diag = (t == nt - 1);
  const bool skipHi = diag && evenU;

  f32x16 sf0 = {}, sf1 = {};
  __builtin_amdgcn_s_setprio(1);
#pragma unroll
  for (int ks = 0; ks < 4; ++ks)
    sf0 = __builtin_amdgcn_mfma_f32_32x32x16_bf16(kf[ks], qf[ks], sf0, 0, 0, 0);
  if (!skipHi) {
#pragma unroll
    for (int ks = 0; ks < 4; ++ks)
      sf1 = __builtin_amdgcn_mfma_f32_32x32x16_bf16(kf[4 + ks], qf[ks], sf1, 0, 0, 0);
  }
  __builtin_amdgcn_s_setprio(0);

  if (diag) {   // causal mask; kv of reg r = 16*(r>>3) + 8*hi + (r&7)
#pragma unroll
    for (int r = 0; r < 16; ++r) {
      const int kvl = (r & 7) + 8 * hi + 16 * (r >> 3);
      if (kv0 + kvl > qrow)      sf0[r] = -1e30f;
      if (kv0 + 32 + kvl > qrow) sf1[r] = -1e30f;
    }
  }

  float rs0 = 0.f, rs1 = 0.f;
#pragma unroll
  for (int r = 0; r < 8; ++r)  { float e = EXP2(sf0[r]); sf0[r] = e; rs0 += e; }
#pragma unroll
  for (int r = 8; r < 16; ++r) { float e = EXP2(sf0[r]); sf0[r] = e; rs1 += e; }
  if (!skipHi) {
#pragma unroll
    for (int r = 0; r < 8; ++r)  { float e = EXP2(sf1[r]); sf1[r] = e; rs0 += e; }
#pragma unroll
    for (int r = 8; r < 16; ++r) { float e = EXP2(sf1[r]); sf1[r] = e; rs1 += e; }
  }
  l_ += rs0 + rs1;

  __builtin_amdgcn_s_setprio(1);
#pragma unroll
  for (int at = 0; at < 2; ++at) {
    if (at == 1 && skipHi) break;
    const f32x16& sfv = at ? sf1 : sf0;
#pragma unroll
    for (int half = 0; half < 2; ++half) {
      const int rb = half * 8;
      u32x4 pw;
      pw[0] = cvtpk_hw(sfv[rb + 0], sfv[rb + 1]);
      pw[1] = cvtpk_hw(sfv[rb + 2], sfv[rb + 3]);
      pw[2] = cvtpk_hw(sfv[rb + 4], sfv[rb + 5]);
      pw[3] = cvtpk_hw(sfv[rb + 6], sfv[rb + 7]);
      const bf16x8 pa = __builtin_bit_cast(bf16x8, pw);
      const int ksg = at * 2 + half;
      acc0 = __builtin_amdgcn_mfma_f32_32x32x16_bf16(pa, vf[ksg], acc0, 0, 0, 0);
      acc1 = __builtin_amdgcn_mfma_f32_32x32x16_bf16(pa, vf[4 + ksg], acc1, 0, 0, 0);
    }
  }
  __builtin_amdgcn_s_setprio(0);
}

// ---------------- causal MQA flash attention: split-KV, 2-wave blocks, LPT ----------------
__global__ __launch_bounds__(128, 2) void attn_kernel(
    const u16* __restrict__ Q,   // [B*S][DM] bf16 (head h at col h*64), pre-scaled
    const u16* __restrict__ KF,  // fragment-linear K (sigma-permuted rows)
    const u16* __restrict__ VF,  // fragment-linear V
    u16* __restrict__ O) {       // [B*S][DM] bf16
  __shared__ float Ll[2][32];
  __shared__ float Lacc[2][32][64];   // 16 KB

  const int j = blockIdx.x, h = blockIdx.y, b = blockIdx.z;
  const int wave = threadIdx.x >> 6, lane = threadIdx.x & 63;
  const int q31 = lane & 31, hi = lane >> 5;

  const int u = 63 - j;                  // LPT order
  const int qrow = u * 32 + q31;
  const int nt = (u + 2) >> 1;           // kv tiles for this q-unit
  const bool evenU = !(u & 1);

  const u16* Qp = Q + (size_t)(b * S_ + qrow) * DM + h * DK;
  bf16x8 qf[4];
#pragma unroll
  for (int ks = 0; ks < 4; ++ks)
    qf[ks] = *(const bf16x8*)(Qp + ks * 16 + hi * 8);

  f32x16 acc0 = {}, acc1 = {};
  float l_ = 0.f;

  const u16* kfb = KF + (size_t)(b * 32) * 4096 + lane * 8;
  const u16* vfb = VF + (size_t)(b * 32) * 4096 + lane * 8;

  bf16x8 kA[8], vA[8], kB[8], vB[8];
  int t = wave;
  if (t < nt)
    attn_load(kfb + (size_t)t * 4096, vfb + (size_t)t * 4096, kA, vA);
  for (; t < nt; t += 4) {
    const int t1 = t + 2;
    if (t1 < nt)
      attn_load(kfb + (size_t)t1 * 4096, vfb + (size_t)t1 * 4096, kB, vB);
    attn_comp(t, qrow, hi, evenU, nt, kA, vA, qf, acc0, acc1, l_);
    if (t1 < nt) {
      const int t2 = t1 + 2;
      if (t2 < nt)
        attn_load(kfb + (size_t)t2 * 4096, vfb + (size_t)t2 * 4096, kA, vA);
      attn_comp(t1, qrow, hi, evenU, nt, kB, vB, qf, acc0, acc1, l_);
    }
  }

  // one lane^32 combine of the per-lane l partials
  l_ += __shfl_xor(l_, 32);

  // ---- block-level combine of the 2 partials (plain sums) ----
  if (hi == 0) Ll[wave][q31] = l_;
  __syncthreads();

#pragma unroll
  for (int r = 0; r < 16; ++r) {
    const int rr = (r & 3) + 8 * (r >> 2) + 4 * hi;   // acc row (PV D layout)
    Lacc[wave][rr][q31]      = acc0[r];
    Lacc[wave][rr][32 + q31] = acc1[r];
  }
  __syncthreads();

  // 128 threads: row = tid>>2 (32 rows), dv0 = (tid&3)*16, 16 elems each
  const int tid = threadIdx.x;
  const int row = tid >> 2;
  const int dv0 = (tid & 3) * 16;
  const float Lr = Ll[0][row] + Ll[1][row];
  const float linv = 1.f / Lr;
  u16 ov[16];
#pragma unroll
  for (int i = 0; i < 16; ++i) {
    const float v = (Lacc[0][row][dv0 + i] + Lacc[1][row][dv0 + i]) * linv;
    ov[i] = f2bf(v);
  }
  u16* Op = O + (size_t)(b * S_ + u * 32 + row) * DM + h * DK + dv0;
  *(bf16x8*)Op       = *(const bf16x8*)ov;
  *(bf16x8*)(Op + 8) = *(const bf16x8*)(ov + 8);
}

// ---------------- launch ----------------
extern "C" void kernel_launch(void* const* d_in, const int* in_sizes, int n_in,
                              void* d_out, int out_size, void* d_ws, size_t ws_size,
                              hipStream_t stream) {
  const float* in_q = (const float*)d_in[0];
  const float* in_k = (const float*)d_in[1];
  const float* in_v = (const float*)d_in[2];
  const float* Wq   = (const float*)d_in[3];
  const float* bq   = (const float*)d_in[4];
  const float* Wk   = (const float*)d_in[5];
  const float* bk   = (const float*)d_in[6];
  const float* Wv   = (const float*)d_in[7];
  const float* bv   = (const float*)d_in[8];
  const float* Wo   = (const float*)d_in[9];
  const float* bo   = (const float*)d_in[10];

  char* ws  = (char*)d_ws;
  u16* Qbf  = (u16*)(ws + OFF_QBF);
  u16* KFp  = (u16*)(ws + OFF_KF);
  u16* VFp  = (u16*)(ws + OFF_VF);
  u16* AObf = (u16*)(ws + OFF_AOBF);
  u16* WqT  = (u16*)(ws + OFF_WQT);
  u16* WoT  = (u16*)(ws + OFF_WOT);
  u16* WkT  = (u16*)(ws + OFF_WKT);
  u16* WvT  = (u16*)(ws + OFF_WVT);
  u16* Xqbf = (u16*)(ws + OFF_XQBF);

  // one launch: all weight transposes + in_q cast
  prep_kernel<<<dim3(32, 32, 5), dim3(32, 8), 0, stream>>>(
      Wq, Wo, Wk, Wv, in_q, WqT, WoT, WkT, WvT, Xqbf);

  // K/V projection reading f32 inputs directly (cast fused into staging)
  kvproj_kernel<<<dim3(M_ / 64, 2), 256, 0, stream>>>(
      in_k, in_v, WkT, WvT, bk, bv, KFp, VFp);

  // Q projection (bf16 A), pre-scaled by 1/sqrt(dk)*log2(e)
  gemm_bf16_kernel<0><<<dim3(M_ / 128, DM / 64), 256, 0, stream>>>(
      Xqbf, WqT, bq, Qbf, M_, DM, DM, 0.125f * 1.44269504088896f);

  attn_kernel<<<dim3(64, H_, B_), 128, 0, stream>>>(Qbf, KFp, VFp, AObf);

  gemm_bf16_kernel<1><<<dim3(M_ / 128, DM / 64), 256, 0, stream>>>(
      AObf, WoT, bo, d_out, M_, DM, DM, 1.0f);
}

// Round 23
// 94.797 us; speedup vs baseline: 1.2945x; 1.1428x over previous
//
#include <hip/hip_runtime.h>
#include <cstdint>
#include <cstddef>

typedef unsigned short u16;
typedef __bf16 bf16x8 __attribute__((ext_vector_type(8)));
typedef float  f32x4  __attribute__((ext_vector_type(4)));
typedef float  f32x16 __attribute__((ext_vector_type(16)));
typedef unsigned u32x4 __attribute__((ext_vector_type(4)));

#define DEV __device__ __forceinline__

#define B_  2
#define S_  2048
#define DM  1024
#define H_  16
#define DK  64
#define M_  (B_ * S_)   // 4096

#if __has_builtin(__builtin_amdgcn_exp2f)
#define EXP2(x) __builtin_amdgcn_exp2f(x)
#else
#define EXP2(x) exp2f(x)
#endif

// ---------------- workspace layout (bytes) ----------------
constexpr size_t OFF_QBF  = 0;                                  // Q proj out bf16 [M][DM]
constexpr size_t OFF_KF   = OFF_QBF  + (size_t)M_ * DM * 2;     // K frag-linear (sigma rows)
constexpr size_t OFF_VF   = OFF_KF   + (size_t)M_ * DK * 2;     // V frag-linear
constexpr size_t OFF_AOBF = OFF_VF   + (size_t)M_ * DK * 2;     // attn out bf16 [M][DM]
constexpr size_t OFF_WQT  = OFF_AOBF + (size_t)M_ * DM * 2;     // Wq^T bf16 [DM][DM]
constexpr size_t OFF_WOT  = OFF_WQT  + (size_t)DM * DM * 2;     // Wo^T bf16 [DM][DM]
constexpr size_t OFF_WKT  = OFF_WOT  + (size_t)DM * DM * 2;     // Wk^T bf16 [DK][DM]
constexpr size_t OFF_WVT  = OFF_WKT  + (size_t)DK * DM * 2;     // Wv^T bf16 [DK][DM]
constexpr size_t OFF_XQBF = OFF_WVT  + (size_t)DK * DM * 2;     // inputs_q bf16 [M][DM]

// ---------------- helpers ----------------
DEV u16 f2bf(float f) {                 // RNE f32 -> bf16
  unsigned u = __float_as_uint(f);
  u += 0x7fffu + ((u >> 16) & 1u);
  return (u16)(u >> 16);
}

DEV unsigned cvtpk(float lo, float hi) { // pack 2 f32 -> 2 bf16 (lo in low 16)
  return (unsigned)f2bf(lo) | ((unsigned)f2bf(hi) << 16);
}

DEV unsigned cvtpk_hw(float lo, float hi) { // v_cvt_pk_bf16_f32 (1 instr)
  unsigned r;
  asm("v_cvt_pk_bf16_f32 %0, %1, %2" : "=v"(r) : "v"(lo), "v"(hi));
  return r;
}

DEV u32x4 pack8(const float4& a, const float4& b) {
  u32x4 w;
  w[0] = cvtpk(a.x, a.y);
  w[1] = cvtpk(a.z, a.w);
  w[2] = cvtpk(b.x, b.y);
  w[3] = cvtpk(b.z, b.w);
  return w;
}

DEV void gload_lds16(const void* g, void* l) {
  __builtin_amdgcn_global_load_lds(
      (const __attribute__((address_space(1))) unsigned int*)g,
      (__attribute__((address_space(3))) unsigned int*)l, 16, 0, 0);
}

// ---------------- shared-memory views for the fused qkv kernel ----------------
struct GemmSmem { u16 At[2][128 * 64]; u16 Bt[2][64 * 64]; };      // 48 KB
struct KvSmem   { u16 At[64 * 32]; u16 Bt[64 * 32]; u16 stage[64][72]; }; // ~17 KB
union QkvSmem { GemmSmem g; KvSmem kv; };

// ---------------- merged prep: 4 weight transposes + in_q cast, one launch ----------------
__global__ __launch_bounds__(256) void prep_kernel(
    const float* __restrict__ Wq, const float* __restrict__ Wo,
    const float* __restrict__ Wk, const float* __restrict__ Wv,
    const float* __restrict__ in_q,
    u16* __restrict__ WqT, u16* __restrict__ WoT,
    u16* __restrict__ WkT, u16* __restrict__ WvT,
    u16* __restrict__ Xq) {
  const int z = blockIdx.z;
  if (z == 4) {                        // cast in_q: 4M f32 -> bf16
    const int tid = (blockIdx.y * 32 + blockIdx.x) * 256 +
                    threadIdx.y * 32 + threadIdx.x;
    const int n8 = M_ * DM / 8;
    for (int i = tid; i < n8; i += 1024 * 256) {
      float4 a = ((const float4*)in_q)[2 * i];
      float4 b = ((const float4*)in_q)[2 * i + 1];
      ((u32x4*)Xq)[i] = pack8(a, b);
    }
    return;
  }
  const float* W; u16* WT; int C;
  if (z == 0)      { W = Wq; WT = WqT; C = DM; }
  else if (z == 1) { W = Wo; WT = WoT; C = DM; }
  else if (z == 2) { W = Wk; WT = WkT; C = DK; }
  else             { W = Wv; WT = WvT; C = DK; }
  const int c0 = blockIdx.x * 32, r0 = blockIdx.y * 32;
  if (c0 >= C) return;                 // block-uniform exit (Wk/Wv: only x<2)
  __shared__ u16 tile[32][33];
  for (int i = threadIdx.y; i < 32; i += 8)
    tile[i][threadIdx.x] = f2bf(W[(size_t)(r0 + i) * C + c0 + threadIdx.x]);
  __syncthreads();
  for (int i = threadIdx.y; i < 32; i += 8)
    WT[(size_t)(c0 + i) * DM + r0 + threadIdx.x] = tile[threadIdx.x][i];
}

// ---------------- K/V projection body (f32 input, fused fragment-linear emit) ----------------
DEV void kvproj_dev(KvSmem& sm,
                    const float* __restrict__ X, const u16* __restrict__ WT,
                    const float* __restrict__ bias,
                    u16* __restrict__ KF, u16* __restrict__ VF,
                    int bm, int sel) {
  const int tid = threadIdx.x, wave = tid >> 6, lane = tid & 63;
  const int g = lane >> 4, c = lane & 15;
  const int wm = wave >> 1, wn = wave & 1;
  f32x4 acc[2][2] = {};

  const int row = tid >> 2, sd = tid & 3;
  const float* Asrc = X + (size_t)(bm * 64 + row) * DM + sd * 8;
  const u16* Bsrc = WT + (size_t)row * DM + ((sd ^ (row & 3)) * 8);
  u16* Adst = sm.At + row * 32 + ((sd ^ (row & 3)) * 8);   // write-side swizzle

  for (int k0 = 0; k0 < DM; k0 += 32) {
    __syncthreads();
    const float4 x0 = *(const float4*)(Asrc + k0);
    const float4 x1 = *(const float4*)(Asrc + k0 + 4);
    gload_lds16(Bsrc + k0, sm.Bt + wave * 512);
    *(u32x4*)Adst = pack8(x0, x1);
    asm volatile("s_waitcnt vmcnt(0)" ::: "memory");
    __syncthreads();

    bf16x8 af[2], bfr[2];
#pragma unroll
    for (int mf = 0; mf < 2; ++mf) {
      const int ra = wm * 32 + mf * 16 + c;
      af[mf] = *(const bf16x8*)(sm.At + ra * 32 + ((g ^ (ra & 3)) * 8));
    }
#pragma unroll
    for (int nf = 0; nf < 2; ++nf) {
      const int rb = wn * 32 + nf * 16 + c;
      bfr[nf] = *(const bf16x8*)(sm.Bt + rb * 32 + ((g ^ (rb & 3)) * 8));
    }
#pragma unroll
    for (int mf = 0; mf < 2; ++mf)
#pragma unroll
      for (int nf = 0; nf < 2; ++nf)
        acc[mf][nf] = __builtin_amdgcn_mfma_f32_16x16x32_bf16(
            af[mf], bfr[nf], acc[mf][nf], 0, 0, 0);
  }

  // stage D-layout output (bias added) into LDS
  __syncthreads();
#pragma unroll
  for (int nf = 0; nf < 2; ++nf) {
    const int col = wn * 32 + nf * 16 + c;
    const float bs = bias[col];
#pragma unroll
    for (int mf = 0; mf < 2; ++mf)
#pragma unroll
      for (int r = 0; r < 4; ++r)
        sm.stage[wm * 32 + mf * 16 + g * 4 + r][col] = f2bf(acc[mf][nf][r] + bs);
  }
  __syncthreads();

  // fragment-linear emit (sigma for K, transpose for V)
  u16* outF = (sel ? VF : KF) + (size_t)bm * 4096;
#pragma unroll
  for (int p = 0; p < 2; ++p) {
    const int id = tid + p * 256;          // (sub,ks,lane)
    const int sub = id >> 8, ks = (id >> 6) & 3, ln = id & 63;
    const int hi2 = ln >> 5, q = ln & 31;
    if (!sel) {   // K: sigma = swap bits 2<->3 of q
      const int sq = (q & ~12) | ((q & 4) << 1) | ((q & 8) >> 1);
      *(bf16x8*)&outF[id * 8] =
          *(const bf16x8*)&sm.stage[sub * 32 + sq][ks * 16 + hi2 * 8];
    } else {      // V: transposed
      u16 tmp[8];
#pragma unroll
      for (int i = 0; i < 8; ++i)
        tmp[i] = sm.stage[ks * 16 + hi2 * 8 + i][sub * 32 + q];
      *(bf16x8*)&outF[id * 8] = *(const bf16x8*)tmp;
    }
  }
}

// ---------------- 2-phase double-buffered 128x64 bf16 GEMM body, BK=64 ----------------
template <int OUT_F32>
DEV void gemm_dev(GemmSmem& sm,
                  const u16* __restrict__ A, const u16* __restrict__ BT,
                  const float* __restrict__ bias, void* __restrict__ Cout,
                  int M, int N, int K, float oscale, int bm, int bn) {
  const int tid = threadIdx.x, wave = tid >> 6, lane = tid & 63;
  const int wm = wave >> 1, wn = wave & 1;
  const int g = lane >> 4, c = lane & 15;
  f32x4 acc[4][2] = {};

  // staging maps (16B bf16 slots, source col pre-swizzled; linear LDS dest)
  int arow[4], acol[4], brow[2], bcol[2];
#pragma unroll
  for (int i = 0; i < 4; ++i) {
    const int sid = (i * 4 + wave) * 64 + lane;   // 0..1023
    arow[i] = sid >> 3;
    acol[i] = ((sid & 7) ^ ((sid >> 3) & 7)) * 8;
  }
#pragma unroll
  for (int i = 0; i < 2; ++i) {
    const int sid = (i * 4 + wave) * 64 + lane;   // 0..511
    brow[i] = sid >> 3;
    bcol[i] = ((sid & 7) ^ ((sid >> 3) & 7)) * 8;
  }
  const int nt = K >> 6;

  auto stage_g = [&](int buf, int t) {
    const int k0_ = t << 6;
#pragma unroll
    for (int i = 0; i < 4; ++i)
      gload_lds16(A + (size_t)(bm * 128 + arow[i]) * K + k0_ + acol[i],
                  &sm.At[buf][(i * 4 + wave) * 512]);
#pragma unroll
    for (int i = 0; i < 2; ++i)
      gload_lds16(BT + (size_t)(bn * 64 + brow[i]) * K + k0_ + bcol[i],
                  &sm.Bt[buf][(i * 4 + wave) * 512]);
  };

  stage_g(0, 0);
  asm volatile("s_waitcnt vmcnt(0)" ::: "memory");
  __syncthreads();

  int cur = 0;
  for (int t = 0; t < nt; ++t) {
    if (t + 1 < nt) stage_g(cur ^ 1, t + 1);   // issue next-tile loads FIRST
#pragma unroll
    for (int kk = 0; kk < 2; ++kk) {
      bf16x8 af[4], bfr[2];
#pragma unroll
      for (int mf = 0; mf < 4; ++mf) {
        const int row = wm * 64 + mf * 16 + c;
        af[mf] = *(const bf16x8*)(&sm.At[cur][row * 64 + ((kk * 4 + g) ^ (row & 7)) * 8]);
      }
#pragma unroll
      for (int nf = 0; nf < 2; ++nf) {
        const int row = wn * 32 + nf * 16 + c;
        bfr[nf] = *(const bf16x8*)(&sm.Bt[cur][row * 64 + ((kk * 4 + g) ^ (row & 7)) * 8]);
      }
#pragma unroll
      for (int mf = 0; mf < 4; ++mf)
#pragma unroll
        for (int nf = 0; nf < 2; ++nf)
          acc[mf][nf] = __builtin_amdgcn_mfma_f32_16x16x32_bf16(
              af[mf], bfr[nf], acc[mf][nf], 0, 0, 0);
    }
    asm volatile("s_waitcnt vmcnt(0)" ::: "memory");  // next tile landed
    __syncthreads();
    cur ^= 1;
  }

  const int colb = bn * 64 + wn * 32 + c;
  const int rowb = bm * 128 + wm * 64 + g * 4;
#pragma unroll
  for (int nf = 0; nf < 2; ++nf) {
    float bs = bias[colb + nf * 16];
#pragma unroll
    for (int mf = 0; mf < 4; ++mf) {
#pragma unroll
      for (int r = 0; r < 4; ++r) {
        size_t idx = (size_t)(rowb + mf * 16 + r) * N + colb + nf * 16;
        float v = (acc[mf][nf][r] + bs) * oscale;
        if (OUT_F32) ((float*)Cout)[idx] = v;
        else         ((u16*)Cout)[idx]   = f2bf(v);
      }
    }
  }
}

// ---------------- fused Q-GEMM + K/V projection: one 640-block dispatch ----------------
// grid (32, 20): y<16 -> Q-GEMM tile (bm=x, bn=y); y>=16 -> kvproj tile
// id = (y-16)*32+x in 0..127 (sel = id>>6, bm = id&63). Branch is block-uniform.
__global__ __launch_bounds__(256) void qkv_fused_kernel(
    const u16* __restrict__ Xq, const u16* __restrict__ WqT,
    const float* __restrict__ bq, u16* __restrict__ Qbf, float qscale,
    const float* __restrict__ Xk, const float* __restrict__ Xv,
    const u16* __restrict__ WkT, const u16* __restrict__ WvT,
    const float* __restrict__ bk, const float* __restrict__ bv,
    u16* __restrict__ KF, u16* __restrict__ VF) {
  __shared__ QkvSmem sm;
  if (blockIdx.y < 16) {
    gemm_dev<0>(sm.g, Xq, WqT, bq, Qbf, M_, DM, DM, qscale,
                blockIdx.x, blockIdx.y);
  } else {
    const int id = (blockIdx.y - 16) * 32 + blockIdx.x;   // 0..127
    const int sel = id >> 6, bm = id & 63;
    kvproj_dev(sm.kv, sel ? Xv : Xk, sel ? WvT : WkT, sel ? bv : bk,
               KF, VF, bm, sel);
  }
}

// ---------------- standalone GEMM kernel (O projection) ----------------
template <int OUT_F32>
__global__ __launch_bounds__(256) void gemm_bf16_kernel(
    const u16* __restrict__ A, const u16* __restrict__ BT,
    const float* __restrict__ bias, void* __restrict__ Cout,
    int M, int N, int K, float oscale) {
  __shared__ GemmSmem sm;
  gemm_dev<OUT_F32>(sm, A, BT, bias, Cout, M, N, K, oscale,
                    blockIdx.x, blockIdx.y);
}

// ---------------- attn: per-tile load / compute building blocks (R14 proven) ----------------
DEV void attn_load(const u16* kp, const u16* vp, bf16x8* kf, bf16x8* vf) {
#pragma unroll
  for (int i = 0; i < 4; ++i) {
    kf[i]     = *(const bf16x8*)(kp + i * 512);
    kf[4 + i] = *(const bf16x8*)(kp + 2048 + i * 512);
    vf[i]     = *(const bf16x8*)(vp + i * 512);
    vf[4 + i] = *(const bf16x8*)(vp + 2048 + i * 512);
  }
}

DEV void attn_comp(int t, int qrow, int hi, bool evenU, int nt,
                   const bf16x8* kf, const bf16x8* vf, const bf16x8* qf,
                   f32x16& acc0, f32x16& acc1, float& l_) {
  const int kv0 = t * 64;
  const bool diag = (t == nt - 1);
  const bool skipHi = diag && evenU;

  f32x16 sf0 = {}, sf1 = {};
  __builtin_amdgcn_s_setprio(1);
#pragma unroll
  for (int ks = 0; ks < 4; ++ks)
    sf0 = __builtin_amdgcn_mfma_f32_32x32x16_bf16(kf[ks], qf[ks], sf0, 0, 0, 0);
  if (!skipHi) {
#pragma unroll
    for (int ks = 0; ks < 4; ++ks)
      sf1 = __builtin_amdgcn_mfma_f32_32x32x16_bf16(kf[4 + ks], qf[ks], sf1, 0, 0, 0);
  }
  __builtin_amdgcn_s_setprio(0);

  if (diag) {   // causal mask; kv of reg r = 16*(r>>3) + 8*hi + (r&7)
#pragma unroll
    for (int r = 0; r < 16; ++r) {
      const int kvl = (r & 7) + 8 * hi + 16 * (r >> 3);
      if (kv0 + kvl > qrow)      sf0[r] = -1e30f;
      if (kv0 + 32 + kvl > qrow) sf1[r] = -1e30f;
    }
  }

  float rs0 = 0.f, rs1 = 0.f;
#pragma unroll
  for (int r = 0; r < 8; ++r)  { float e = EXP2(sf0[r]); sf0[r] = e; rs0 += e; }
#pragma unroll
  for (int r = 8; r < 16; ++r) { float e = EXP2(sf0[r]); sf0[r] = e; rs1 += e; }
  if (!skipHi) {
#pragma unroll
    for (int r = 0; r < 8; ++r)  { float e = EXP2(sf1[r]); sf1[r] = e; rs0 += e; }
#pragma unroll
    for (int r = 8; r < 16; ++r) { float e = EXP2(sf1[r]); sf1[r] = e; rs1 += e; }
  }
  l_ += rs0 + rs1;

  __builtin_amdgcn_s_setprio(1);
#pragma unroll
  for (int at = 0; at < 2; ++at) {
    if (at == 1 && skipHi) break;
    const f32x16& sfv = at ? sf1 : sf0;
#pragma unroll
    for (int half = 0; half < 2; ++half) {
      const int rb = half * 8;
      u32x4 pw;
      pw[0] = cvtpk_hw(sfv[rb + 0], sfv[rb + 1]);
      pw[1] = cvtpk_hw(sfv[rb + 2], sfv[rb + 3]);
      pw[2] = cvtpk_hw(sfv[rb + 4], sfv[rb + 5]);
      pw[3] = cvtpk_hw(sfv[rb + 6], sfv[rb + 7]);
      const bf16x8 pa = __builtin_bit_cast(bf16x8, pw);
      const int ksg = at * 2 + half;
      acc0 = __builtin_amdgcn_mfma_f32_32x32x16_bf16(pa, vf[ksg], acc0, 0, 0, 0);
      acc1 = __builtin_amdgcn_mfma_f32_32x32x16_bf16(pa, vf[4 + ksg], acc1, 0, 0, 0);
    }
  }
  __builtin_amdgcn_s_setprio(0);
}

// ---------------- causal MQA flash attention: split-KV, 2-wave blocks, LPT ----------------
__global__ __launch_bounds__(128, 2) void attn_kernel(
    const u16* __restrict__ Q,   // [B*S][DM] bf16 (head h at col h*64), pre-scaled
    const u16* __restrict__ KF,  // fragment-linear K (sigma-permuted rows)
    const u16* __restrict__ VF,  // fragment-linear V
    u16* __restrict__ O) {       // [B*S][DM] bf16
  __shared__ float Ll[2][32];
  __shared__ float Lacc[2][32][64];   // 16 KB

  const int j = blockIdx.x, h = blockIdx.y, b = blockIdx.z;
  const int wave = threadIdx.x >> 6, lane = threadIdx.x & 63;
  const int q31 = lane & 31, hi = lane >> 5;

  const int u = 63 - j;                  // LPT order
  const int qrow = u * 32 + q31;
  const int nt = (u + 2) >> 1;           // kv tiles for this q-unit
  const bool evenU = !(u & 1);

  const u16* Qp = Q + (size_t)(b * S_ + qrow) * DM + h * DK;
  bf16x8 qf[4];
#pragma unroll
  for (int ks = 0; ks < 4; ++ks)
    qf[ks] = *(const bf16x8*)(Qp + ks * 16 + hi * 8);

  f32x16 acc0 = {}, acc1 = {};
  float l_ = 0.f;

  const u16* kfb = KF + (size_t)(b * 32) * 4096 + lane * 8;
  const u16* vfb = VF + (size_t)(b * 32) * 4096 + lane * 8;

  bf16x8 kA[8], vA[8], kB[8], vB[8];
  int t = wave;
  if (t < nt)
    attn_load(kfb + (size_t)t * 4096, vfb + (size_t)t * 4096, kA, vA);
  for (; t < nt; t += 4) {
    const int t1 = t + 2;
    if (t1 < nt)
      attn_load(kfb + (size_t)t1 * 4096, vfb + (size_t)t1 * 4096, kB, vB);
    attn_comp(t, qrow, hi, evenU, nt, kA, vA, qf, acc0, acc1, l_);
    if (t1 < nt) {
      const int t2 = t1 + 2;
      if (t2 < nt)
        attn_load(kfb + (size_t)t2 * 4096, vfb + (size_t)t2 * 4096, kA, vA);
      attn_comp(t1, qrow, hi, evenU, nt, kB, vB, qf, acc0, acc1, l_);
    }
  }

  // one lane^32 combine of the per-lane l partials
  l_ += __shfl_xor(l_, 32);

  // ---- block-level combine of the 2 partials (plain sums) ----
  if (hi == 0) Ll[wave][q31] = l_;
  __syncthreads();

#pragma unroll
  for (int r = 0; r < 16; ++r) {
    const int rr = (r & 3) + 8 * (r >> 2) + 4 * hi;   // acc row (PV D layout)
    Lacc[wave][rr][q31]      = acc0[r];
    Lacc[wave][rr][32 + q31] = acc1[r];
  }
  __syncthreads();

  // 128 threads: row = tid>>2 (32 rows), dv0 = (tid&3)*16, 16 elems each
  const int tid = threadIdx.x;
  const int row = tid >> 2;
  const int dv0 = (tid & 3) * 16;
  const float Lr = Ll[0][row] + Ll[1][row];
  const float linv = 1.f / Lr;
  u16 ov[16];
#pragma unroll
  for (int i = 0; i < 16; ++i) {
    const float v = (Lacc[0][row][dv0 + i] + Lacc[1][row][dv0 + i]) * linv;
    ov[i] = f2bf(v);
  }
  u16* Op = O + (size_t)(b * S_ + u * 32 + row) * DM + h * DK + dv0;
  *(bf16x8*)Op       = *(const bf16x8*)ov;
  *(bf16x8*)(Op + 8) = *(const bf16x8*)(ov + 8);
}

// ---------------- launch ----------------
extern "C" void kernel_launch(void* const* d_in, const int* in_sizes, int n_in,
                              void* d_out, int out_size, void* d_ws, size_t ws_size,
                              hipStream_t stream) {
  const float* in_q = (const float*)d_in[0];
  const float* in_k = (const float*)d_in[1];
  const float* in_v = (const float*)d_in[2];
  const float* Wq   = (const float*)d_in[3];
  const float* bq   = (const float*)d_in[4];
  const float* Wk   = (const float*)d_in[5];
  const float* bk   = (const float*)d_in[6];
  const float* Wv   = (const float*)d_in[7];
  const float* bv   = (const float*)d_in[8];
  const float* Wo   = (const float*)d_in[9];
  const float* bo   = (const float*)d_in[10];

  char* ws  = (char*)d_ws;
  u16* Qbf  = (u16*)(ws + OFF_QBF);
  u16* KFp  = (u16*)(ws + OFF_KF);
  u16* VFp  = (u16*)(ws + OFF_VF);
  u16* AObf = (u16*)(ws + OFF_AOBF);
  u16* WqT  = (u16*)(ws + OFF_WQT);
  u16* WoT  = (u16*)(ws + OFF_WOT);
  u16* WkT  = (u16*)(ws + OFF_WKT);
  u16* WvT  = (u16*)(ws + OFF_WVT);
  u16* Xqbf = (u16*)(ws + OFF_XQBF);

  // one launch: all weight transposes + in_q cast
  prep_kernel<<<dim3(32, 32, 5), dim3(32, 8), 0, stream>>>(
      Wq, Wo, Wk, Wv, in_q, WqT, WoT, WkT, WvT, Xqbf);

  // one launch: Q projection (bf16 A, pre-scaled 1/8*log2e) + K/V projection
  qkv_fused_kernel<<<dim3(32, 20), 256, 0, stream>>>(
      Xqbf, WqT, bq, Qbf, 0.125f * 1.44269504088896f,
      in_k, in_v, WkT, WvT, bk, bv, KFp, VFp);

  attn_kernel<<<dim3(64, H_, B_), 128, 0, stream>>>(Qbf, KFp, VFp, AObf);

  gemm_bf16_kernel<1><<<dim3(M_ / 128, DM / 64), 256, 0, stream>>>(
      AObf, WoT, bo, d_out, M_, DM, DM, 1.0f);
}